// Round 18
// baseline (278.140 us; speedup 1.0000x reference)
//
#include <hip/hip_runtime.h>

#define BB 64
#define CC 96
#define HH 56
#define WW 56
#define HWSZ (HH*WW)          // 3136
#define CHW (CC*HWSZ)         // 301056
#define NTOT ((size_t)BB*CHW) // 19267584
#define S_SPLIT 32
#define CHUNK (CHW/S_SPLIT)   // 9408
#define HD 384
#define NP 104                // LDS row pitch (ushorts): 208B rows, 16B-aligned

typedef float f32x4  __attribute__((ext_vector_type(4)));
typedef float f32x4v __attribute__((ext_vector_type(4)));
typedef short bf16x8 __attribute__((ext_vector_type(8)));
typedef unsigned short u16x4 __attribute__((ext_vector_type(4)));

__device__ __forceinline__ unsigned short f2bf(float f) {
    unsigned int u = __float_as_uint(f);
    u = (u + 0x7FFFu + ((u >> 16) & 1u)) >> 16;   // RNE
    return (unsigned short)u;
}
// HW packed convert: 2 f32 -> packed 2x bf16 (RNE), ONE VALU op
__device__ __forceinline__ unsigned int cvtpk(float lo, float hi) {
    unsigned int r;
    asm("v_cvt_pk_bf16_f32 %0, %1, %2" : "=v"(r) : "v"(lo), "v"(hi));
    return r;
}
__device__ __forceinline__ unsigned short cvt1(float x) {
    return (unsigned short)cvtpk(x, x);
}
__device__ __forceinline__ float bf2f(unsigned short u) {
    return __uint_as_float(((unsigned int)u) << 16);
}
// tanh-approx GELU: |err| vs exact erf-gelu ~1e-3.
__device__ __forceinline__ float gelu_t(float x) {
    float s = x*x;
    float q = __builtin_fmaf(s, 0.102943f, 2.3021953f) * x;   // 2y*log2e
    float t = exp2f(q);
    float r = __builtin_amdgcn_rcpf(1.0f + t);
    return __builtin_fmaf(-x, r, x);                          // x - x/(1+e^{2y})
}
__device__ __forceinline__ bf16x8 ldfrag(const unsigned short* p) {
    return *reinterpret_cast<const bf16x8*>(p);
}
// inline GN-stats finalize (wave-local; safe when b is wave-uniform)
template<int NPART>
__device__ __forceinline__ float2 stats_from_parts(const float2* __restrict__ part, int b) {
    int lane = threadIdx.x & 63;
    float s = 0.f, q = 0.f;
    for (int i = lane; i < NPART; i += 64) {
        float2 v = part[b*NPART + i];
        s += v.x; q += v.y;
    }
    #pragma unroll
    for (int off = 32; off > 0; off >>= 1) {
        s += __shfl_down(s, off);
        q += __shfl_down(q, off);
    }
    s = __shfl(s, 0); q = __shfl(q, 0);
    float mean = s / (float)CHW;
    float var  = q / (float)CHW - mean*mean;
    return make_float2(mean, rsqrtf(var + 1e-5f));
}

// ================= weight pre-convert + MFMA-fragment repack (once) =================
__global__ __launch_bounds__(256) void wconv(const float* __restrict__ c1w, const float* __restrict__ c21w,
        const float* __restrict__ c22w, const float* __restrict__ c3w,
        const float* __restrict__ f1w, const float* __restrict__ f2w,
        unsigned short* __restrict__ wbf) {
    int i = blockIdx.x*256 + threadIdx.x;           // 110592 total
    int blk = i / 9216;
    int idx = i - blk*9216;
    int tm   = idx / 1536;
    int rem  = idx - tm*1536;
    int ks   = rem / 512;
    int rem2 = rem - ks*512;
    int lane = rem2 >> 3;
    int j    = rem2 & 7;
    int row = tm*16 + (lane & 15);
    int col = ks*32 + (lane >> 4)*8 + j;
    float v;
    if      (blk == 0) v = c1w [row*CC + col];
    else if (blk == 1) v = c21w[row*CC + col];
    else if (blk == 2) v = c22w[row*CC + col];
    else if (blk == 3) v = c3w [row*CC + col];
    else if (blk <  8) v = f1w[((blk-4)*CC + row)*CC + col];
    else               v = f2w[row*HD + (blk-8)*CC + col];
    wbf[i] = f2bf(v);
}

// ================= GN stats on x, float4 =================
__global__ __launch_bounds__(256) void gn_partial(const float* __restrict__ in, float2* __restrict__ part) {
    int b = blockIdx.y, s = blockIdx.x;
    const float4* p = (const float4*)(in + (size_t)b*CHW + (size_t)s*CHUNK);
    float sum = 0.f, sq = 0.f;
    for (int i = threadIdx.x; i < CHUNK/4; i += 256) {
        float4 v = p[i];
        sum += v.x+v.y+v.z+v.w;
        sq  += v.x*v.x+v.y*v.y+v.z*v.z+v.w*v.w;
    }
    #pragma unroll
    for (int off = 32; off > 0; off >>= 1) {
        sum += __shfl_down(sum, off);
        sq  += __shfl_down(sq,  off);
    }
    __shared__ float2 red[4];
    int wid = threadIdx.x >> 6, lane = threadIdx.x & 63;
    if (lane == 0) red[wid] = make_float2(sum, sq);
    __syncthreads();
    if (threadIdx.x == 0) {
        for (int i = 1; i < 4; i++) { sum += red[i].x; sq += red[i].y; }
        part[b*S_SPLIT + s] = make_float2(sum, sq);
    }
}

// ================= batch-paired 1x1 conv, M-split waves, 4-col vectorized staging =================
template<bool IN_BF, bool OUT_RES, int NPART>
__global__ __launch_bounds__(256) void convk(const void* __restrict__ in_,
        const unsigned short* __restrict__ wbf, const float* __restrict__ bias,
        const float2* __restrict__ part_in, const float* __restrict__ gam, const float* __restrict__ bet,
        const float* __restrict__ res, void* __restrict__ out_, float2* __restrict__ part_out) {
    __shared__ unsigned short xs[128][NP];
    __shared__ float af0[CC], bf0[CC], af1[CC], bf1[CC];
    __shared__ float2 red[4];
    int tid = threadIdx.x;
    int b0 = blockIdx.y, b1 = b0 + 32;
    int hw0 = blockIdx.x * 64;
    int lane = tid & 63, wv = tid >> 6;
    int mh = wv >> 1, cg = wv & 1;
    bf16x8 wfr[9];
    {
        const unsigned short* wl = wbf + mh*4608 + lane*8;
        #pragma unroll
        for (int i = 0; i < 9; i++) wfr[i] = ldfrag(wl + i*512);
    }
    float2 st0 = stats_from_parts<NPART>(part_in, b0);
    float2 st1 = stats_from_parts<NPART>(part_in, b1);
    if (tid < CC) {
        float a0 = st0.y * gam[tid];
        af0[tid] = a0; bf0[tid] = __builtin_fmaf(-st0.x, a0, bet[tid]);
        float a1 = st1.y * gam[tid];
        af1[tid] = a1; bf1[tid] = __builtin_fmaf(-st1.x, a1, bet[tid]);
    }
    __syncthreads();
    {
        // 4 cols/thread per c-plane: float4 (f32) or u16x4 (bf16) loads
        int colq = (tid & 15) * 4;
        for (int c4 = (tid >> 4)*4; c4 < CC; c4 += 64) {
            float v0[4][4], v1[4][4];
            #pragma unroll
            for (int j = 0; j < 4; j++) {
                int c = c4 + j;
                size_t off0 = (size_t)b0*CHW + (size_t)c*HWSZ + hw0 + colq;
                size_t off1 = (size_t)b1*CHW + (size_t)c*HWSZ + hw0 + colq;
                if (IN_BF) {
                    u16x4 u0 = *reinterpret_cast<const u16x4*>((const unsigned short*)in_ + off0);
                    u16x4 u1 = *reinterpret_cast<const u16x4*>((const unsigned short*)in_ + off1);
                    #pragma unroll
                    for (int jj = 0; jj < 4; jj++) {
                        v0[j][jj] = __builtin_fmaf(bf2f((unsigned short)u0[jj]), af0[c], bf0[c]);
                        v1[j][jj] = __builtin_fmaf(bf2f((unsigned short)u1[jj]), af1[c], bf1[c]);
                    }
                } else {
                    f32x4v f0 = *reinterpret_cast<const f32x4v*>((const float*)in_ + off0);
                    f32x4v f1 = *reinterpret_cast<const f32x4v*>((const float*)in_ + off1);
                    #pragma unroll
                    for (int jj = 0; jj < 4; jj++) {
                        v0[j][jj] = __builtin_fmaf(f0[jj], af0[c], bf0[c]);
                        v1[j][jj] = __builtin_fmaf(f1[jj], af1[c], bf1[c]);
                    }
                }
            }
            #pragma unroll
            for (int jj = 0; jj < 4; jj++) {
                *reinterpret_cast<uint2*>(&xs[colq+jj][c4]) =
                    make_uint2(cvtpk(v0[0][jj],v0[1][jj]), cvtpk(v0[2][jj],v0[3][jj]));
                *reinterpret_cast<uint2*>(&xs[64+colq+jj][c4]) =
                    make_uint2(cvtpk(v1[0][jj],v1[1][jj]), cvtpk(v1[2][jj],v1[3][jj]));
            }
        }
    }
    __syncthreads();
    int ln = lane & 15, k0 = (lane >> 4)*8, r0i = (lane >> 4)*4;
    f32x4 acc[3][4];
    #pragma unroll
    for (int t = 0; t < 3; t++)
        #pragma unroll
        for (int x = 0; x < 4; x++) acc[t][x] = (f32x4){0,0,0,0};
    __builtin_amdgcn_s_setprio(1);
    #pragma unroll
    for (int ks = 0; ks < 3; ks++) {
        bf16x8 bfr[4];
        #pragma unroll
        for (int xr = 0; xr < 4; xr++) bfr[xr] = ldfrag(&xs[cg*64 + xr*16 + ln][ks*32+k0]);
        #pragma unroll
        for (int tm = 0; tm < 3; tm++) {
            #pragma unroll
            for (int xr = 0; xr < 4; xr++)
                acc[tm][xr] = __builtin_amdgcn_mfma_f32_16x16x32_bf16(wfr[tm*3+ks], bfr[xr], acc[tm][xr], 0, 0, 0);
        }
    }
    __builtin_amdgcn_s_setprio(0);
    size_t obase = (size_t)(cg ? b1 : b0)*CHW + hw0;
    float s = 0.f, q = 0.f;
    #pragma unroll
    for (int tm = 0; tm < 3; tm++) {
        #pragma unroll
        for (int xr = 0; xr < 4; xr++) {
            #pragma unroll
            for (int r = 0; r < 4; r++) {
                int o = mh*48 + tm*16 + r0i + r;
                size_t idx = obase + (size_t)o*HWSZ + xr*16 + ln;
                float v = acc[tm][xr][r] + bias[o];
                if (OUT_RES) { v += res[idx]; ((float*)out_)[idx] = v; }
                else         { ((unsigned short*)out_)[idx] = cvt1(v); }
                s += v; q += v*v;
            }
        }
    }
    #pragma unroll
    for (int off = 32; off > 0; off >>= 1) { s += __shfl_down(s, off); q += __shfl_down(q, off); }
    if (lane == 0) red[wv] = make_float2(s, q);
    __syncthreads();
    if (tid == 0) {
        part_out[b0*49 + blockIdx.x] = make_float2(red[0].x + red[2].x, red[0].y + red[2].y);
        part_out[b1*49 + blockIdx.x] = make_float2(red[1].x + red[3].x, red[1].y + red[3].y);
    }
}

// ================= depthwise 3x3: vectorized stage-in =================
__global__ __launch_bounds__(256) void dw_fused(const unsigned short* __restrict__ t1,
        const float* __restrict__ dww, const float* __restrict__ dwb,
        const float2* __restrict__ part_in, const float* __restrict__ gam, const float* __restrict__ bet,
        unsigned short* __restrict__ t2, float2* __restrict__ part_out) {
    __shared__ float tile[HH*57];
    __shared__ float2 red[4];
    int bc = blockIdx.x;
    int b = bc / CC, c = bc - b*CC;
    int tid = threadIdx.x;
    float2 st = stats_from_parts<49>(part_in, b);
    float ga = gam[c]*st.y;
    float bb = __builtin_fmaf(-st.x, ga, bet[c]);
    const unsigned short* ip = t1 + (size_t)bc*HWSZ;
    for (int i = tid; i < HWSZ/4; i += 256) {
        u16x4 v = *reinterpret_cast<const u16x4*>(ip + (size_t)i*4);
        int h = i / 14;
        int w0 = (i - h*14)*4;
        float* tp = &tile[h*57 + w0];
        #pragma unroll
        for (int j = 0; j < 4; j++)
            tp[j] = gelu_t(__builtin_fmaf(bf2f((unsigned short)v[j]), ga, bb));
    }
    __syncthreads();
    float w00=dww[c*9+0],w01=dww[c*9+1],w02=dww[c*9+2],
          w10=dww[c*9+3],w11=dww[c*9+4],w12=dww[c*9+5],
          w20=dww[c*9+6],w21=dww[c*9+7],w22=dww[c*9+8];
    float bs = dwb[c];
    unsigned short* op = t2 + (size_t)bc*HWSZ;
    float s = 0.f, q = 0.f;
    for (int i = tid; i < HWSZ; i += 256) {
        int h = i/WW, w_ = i - h*WW;
        float acc = bs;
        int up = h > 0, dn = h < HH-1, lf = w_ > 0, rt = w_ < WW-1;
        const float* rm = &tile[(h-1)*57 + w_];
        const float* r0p = &tile[h*57 + w_];
        const float* rp = &tile[(h+1)*57 + w_];
        if (up) { if (lf) acc += rm[-1]*w00; acc += rm[0]*w01; if (rt) acc += rm[1]*w02; }
        if (lf) acc += r0p[-1]*w10;
        acc += r0p[0]*w11;
        if (rt) acc += r0p[1]*w12;
        if (dn) { if (lf) acc += rp[-1]*w20; acc += rp[0]*w21; if (rt) acc += rp[1]*w22; }
        op[i] = cvt1(acc);
        s += acc; q += acc*acc;
    }
    #pragma unroll
    for (int off = 32; off > 0; off >>= 1) { s += __shfl_down(s, off); q += __shfl_down(q, off); }
    int wid = tid >> 6, lane = tid & 63;
    if (lane == 0) red[wid] = make_float2(s, q);
    __syncthreads();
    if (tid == 0) {
        for (int i = 1; i < 4; i++) { s += red[i].x; q += red[i].y; }
        part_out[bc] = make_float2(s, q);   // indexed [b*96+c]
    }
}

// ================= merged LIF: 2 planes/block, H-scan & W-scan on SEPARATE waves (concurrent) =================
// 256 threads: threads [pl*128, pl*128+128) own plane pl (bc = blockIdx.x*2 + pl).
// Per plane: wave role 0 = H-scan -> spA; wave role 1 = W-scan -> spB (tile is read-only for both).
__global__ __launch_bounds__(256) void lif_hw(const unsigned short* __restrict__ t2,
        unsigned char* __restrict__ xlr, unsigned char* __restrict__ xtd,
        const float2* __restrict__ part_in, const float* __restrict__ gam, const float* __restrict__ bet,
        const float* __restrict__ tau1p, const float* __restrict__ vth1p,
        const float* __restrict__ tau2p, const float* __restrict__ vth2p) {
    __shared__ unsigned short tile[2][HH*58];
    __shared__ unsigned char  spA[2][HH*60];
    __shared__ unsigned char  spB[2][HH*60];
    int tid = threadIdx.x;
    int pl = tid >> 7;                 // plane within block
    int lt = tid & 127;                // local tid within plane group
    int bc = blockIdx.x*2 + pl;
    int b = bc / CC, c = bc - b*CC;
    float2 st = stats_from_parts<96>(part_in, b);   // wave-uniform b -> wave shuffle OK
    float ga = gam[c]*st.y;
    float bb = __builtin_fmaf(-st.x, ga, bet[c]);
    const unsigned short* ip = t2 + (size_t)bc*HWSZ;
    for (int i = lt; i < HWSZ/4; i += 128) {
        u16x4 v = *reinterpret_cast<const u16x4*>(ip + (size_t)i*4);
        int h = i / 14;
        int w0 = (i - h*14)*4;
        unsigned short* tp = &tile[pl][h*58 + w0];
        #pragma unroll
        for (int j = 0; j < 4; j++)
            tp[j] = cvt1(gelu_t(__builtin_fmaf(bf2f((unsigned short)v[j]), ga, bb)));
    }
    __syncthreads();                   // tiles staged
    {
        int role = (tid >> 6) & 1;     // 0: H-scan, 1: W-scan (different waves -> concurrent)
        int lane = tid & 63;
        if (role == 0) {
            const float tau1 = *tau1p, vth1 = *vth1p;
            if (lane < WW) {
                float u = 0.f, o = 0.f;
                #pragma unroll 4
                for (int h = 0; h < HH; h++) {
                    float xv = bf2f(tile[pl][h*58 + lane]);
                    u = xv + tau1*u*(1.f - o);
                    o = (u - vth1 > 0.f) ? 1.f : 0.f;
                    spA[pl][h*60 + lane] = (o != 0.f) ? 1 : 0;
                }
            }
        } else {
            const float tau2 = *tau2p, vth2 = *vth2p;
            if (lane < HH) {
                float u = 0.f, o = 0.f;
                int off = lane*58;
                #pragma unroll 4
                for (int w_ = 0; w_ < WW; w_++) {
                    float xv = bf2f(tile[pl][off + w_]);
                    u = xv + tau2*u*(1.f - o);
                    o = (u - vth2 > 0.f) ? 1.f : 0.f;
                    spB[pl][lane*60 + w_] = (o != 0.f) ? 1 : 0;
                }
            }
        }
    }
    __syncthreads();                   // spA/spB complete
    size_t base = (size_t)bc*HWSZ;
    unsigned int* lr32 = (unsigned int*)(xlr + base);
    unsigned int* td32 = (unsigned int*)(xtd + base);
    for (int i = lt; i < HWSZ/4; i += 128) {   // i*4 = h*56 + w0
        int h = i / 14;
        int w0 = (i - h*14)*4;
        const unsigned char* pa = &spA[pl][h*60 + w0];
        const unsigned char* pb = &spB[pl][h*60 + w0];
        unsigned int a = (unsigned int)pa[0] | ((unsigned int)pa[1]<<8)
                       | ((unsigned int)pa[2]<<16) | ((unsigned int)pa[3]<<24);
        unsigned int t = (unsigned int)pb[0] | ((unsigned int)pb[1]<<8)
                       | ((unsigned int)pb[2]<<16) | ((unsigned int)pb[3]<<24);
        lr32[i] = a;
        td32[i] = t;
    }
}

// ================= dual conv: u8 spike inputs (bit-test -> bf16) =================
__global__ __launch_bounds__(256) void dual_mfma(const unsigned char* __restrict__ xa_g, const unsigned char* __restrict__ xb_g,
        const unsigned short* __restrict__ w1bf, const float* __restrict__ b1,
        const unsigned short* __restrict__ w2bf, const float* __restrict__ b2,
        unsigned short* __restrict__ out, float2* __restrict__ part_out) {
    __shared__ unsigned short xa[64][NP];
    __shared__ unsigned short xb[64][NP];
    __shared__ float2 red[4];
    int tid = threadIdx.x;
    int b = blockIdx.y;
    int hw0 = blockIdx.x * 64;
    {
        int colq = (tid & 15) * 4;
        const unsigned char* ap = xa_g + (size_t)b*CHW + hw0 + colq;
        const unsigned char* bp = xb_g + (size_t)b*CHW + hw0 + colq;
        for (int c4 = (tid >> 4)*4; c4 < CC; c4 += 64) {
            unsigned int ua[4], ub[4];
            #pragma unroll
            for (int j = 0; j < 4; j++) {
                ua[j] = *reinterpret_cast<const unsigned int*>(ap + (size_t)(c4+j)*HWSZ);
                ub[j] = *reinterpret_cast<const unsigned int*>(bp + (size_t)(c4+j)*HWSZ);
            }
            #pragma unroll
            for (int jj = 0; jj < 4; jj++) {
                unsigned int sh = jj*8;
                unsigned int la = (((ua[0]>>sh)&1u)*0x3F80u) | (((ua[1]>>sh)&1u)*0x3F800000u);
                unsigned int ha = (((ua[2]>>sh)&1u)*0x3F80u) | (((ua[3]>>sh)&1u)*0x3F800000u);
                unsigned int lb = (((ub[0]>>sh)&1u)*0x3F80u) | (((ub[1]>>sh)&1u)*0x3F800000u);
                unsigned int hb = (((ub[2]>>sh)&1u)*0x3F80u) | (((ub[3]>>sh)&1u)*0x3F800000u);
                *reinterpret_cast<uint2*>(&xa[colq+jj][c4]) = make_uint2(la, ha);
                *reinterpret_cast<uint2*>(&xb[colq+jj][c4]) = make_uint2(lb, hb);
            }
        }
    }
    __syncthreads();
    int lane = tid & 63, wv = tid >> 6;
    int mh = wv >> 1, cg = wv & 1;
    int ln = lane & 15, k0 = (lane >> 4)*8, r0i = (lane >> 4)*4;
    const unsigned short* wl1 = w1bf + mh*4608 + lane*8;
    const unsigned short* wl2 = w2bf + mh*4608 + lane*8;
    f32x4 acc1[3][2], acc2[3][2];
    #pragma unroll
    for (int t = 0; t < 3; t++) {
        acc1[t][0] = (f32x4){0,0,0,0}; acc1[t][1] = (f32x4){0,0,0,0};
        acc2[t][0] = (f32x4){0,0,0,0}; acc2[t][1] = (f32x4){0,0,0,0};
    }
    __builtin_amdgcn_s_setprio(1);
    #pragma unroll
    for (int ks = 0; ks < 3; ks++) {
        bf16x8 bfa0 = ldfrag(&xa[cg*32 + ln][ks*32+k0]);
        bf16x8 bfa1 = ldfrag(&xa[cg*32 + 16 + ln][ks*32+k0]);
        bf16x8 bfb0 = ldfrag(&xb[cg*32 + ln][ks*32+k0]);
        bf16x8 bfb1 = ldfrag(&xb[cg*32 + 16 + ln][ks*32+k0]);
        #pragma unroll
        for (int tm = 0; tm < 3; tm++) {
            bf16x8 af1 = ldfrag(wl1 + (tm*3+ks)*512);
            bf16x8 af2 = ldfrag(wl2 + (tm*3+ks)*512);
            acc1[tm][0] = __builtin_amdgcn_mfma_f32_16x16x32_bf16(af1, bfa0, acc1[tm][0], 0, 0, 0);
            acc1[tm][1] = __builtin_amdgcn_mfma_f32_16x16x32_bf16(af1, bfa1, acc1[tm][1], 0, 0, 0);
            acc2[tm][0] = __builtin_amdgcn_mfma_f32_16x16x32_bf16(af2, bfb0, acc2[tm][0], 0, 0, 0);
            acc2[tm][1] = __builtin_amdgcn_mfma_f32_16x16x32_bf16(af2, bfb1, acc2[tm][1], 0, 0, 0);
        }
    }
    __builtin_amdgcn_s_setprio(0);
    size_t ob = (size_t)b*CHW + hw0;
    float s = 0.f, q = 0.f;
    #pragma unroll
    for (int tm = 0; tm < 3; tm++) {
        #pragma unroll
        for (int xr = 0; xr < 2; xr++) {
            #pragma unroll
            for (int r = 0; r < 4; r++) {
                int o = mh*48 + tm*16 + r0i + r;
                float v = gelu_t(acc1[tm][xr][r] + b1[o]) + gelu_t(acc2[tm][xr][r] + b2[o]);
                out[ob + (size_t)o*HWSZ + cg*32 + xr*16 + ln] = cvt1(v);
                s += v; q += v*v;
            }
        }
    }
    #pragma unroll
    for (int off = 32; off > 0; off >>= 1) { s += __shfl_down(s, off); q += __shfl_down(q, off); }
    if (lane == 0) red[wv] = make_float2(s, q);
    __syncthreads();
    if (tid == 0) {
        for (int i = 1; i < 4; i++) { s += red[i].x; q += red[i].y; }
        part_out[b*49 + blockIdx.x] = make_float2(s, q);
    }
}

// ================= fused MLP: single batch/block, 256 threads (R15/R17 measured-best config) =================
__global__ __launch_bounds__(256, 6) void mlp_mfma(float* __restrict__ xio, const float2* __restrict__ part_in,
        const float* __restrict__ gam, const float* __restrict__ bet,
        const unsigned short* __restrict__ wbf, const float* __restrict__ b1, const float* __restrict__ b2) {
    __shared__ unsigned short xs[64][NP];   // 13312 B
    __shared__ unsigned short mc[64][NP];   // 13312 B
    __shared__ float afc[CC], bfc[CC];      // +1024 -> 27648 B total, 5 blocks/CU
    int tid = threadIdx.x;
    int b = blockIdx.y;
    int hw0 = blockIdx.x * 64;
    int lane = tid & 63, wv = tid >> 6;
    int mh = wv >> 1;                 // M-half: rows mh*48..mh*48+47
    int cg = wv & 1;                  // col-half: cols cg*32..cg*32+31
    float2 st = stats_from_parts<49>(part_in, b);
    if (tid < CC) {
        float a = st.y * gam[tid];
        afc[tid] = a; bfc[tid] = __builtin_fmaf(-st.x, a, bet[tid]);
    }
    __syncthreads();
    {
        int col = tid & 63;
        size_t base = (size_t)b*CHW + hw0 + col;
        for (int c4 = (tid >> 6)*4; c4 < CC; c4 += 16) {
            float v[4];
            #pragma unroll
            for (int j = 0; j < 4; j++) {
                int c = c4 + j;
                float rv = xio[base + (size_t)c*HWSZ];
                v[j] = __builtin_fmaf(rv, afc[c], bfc[c]);
            }
            *reinterpret_cast<uint2*>(&xs[col][c4]) =
                make_uint2(cvtpk(v[0],v[1]), cvtpk(v[2],v[3]));
        }
    }
    __syncthreads();                   // xs fully staged
    int ln = lane & 15, k0 = (lane >> 4)*8;
    int r0i = (lane >> 4)*4;
    int xrow0 = cg*32 + ln;
    int xrow1 = xrow0 + 16;
    f32x4 ao[3][2];
    #pragma unroll
    for (int t = 0; t < 3; t++) { ao[t][0] = (f32x4){0,0,0,0}; ao[t][1] = (f32x4){0,0,0,0}; }
    for (int ch = 0; ch < 4; ch++) {
        const unsigned short* w1l = wbf + (4+ch)*9216 + mh*4608 + lane*8;
        const unsigned short* w2l = wbf + (8+ch)*9216 + mh*4608 + lane*8;
        f32x4 c1[3][2];
        #pragma unroll
        for (int t = 0; t < 3; t++) { c1[t][0] = (f32x4){0,0,0,0}; c1[t][1] = (f32x4){0,0,0,0}; }
        __builtin_amdgcn_s_setprio(1);
        #pragma unroll
        for (int ks = 0; ks < 3; ks++) {
            bf16x8 bfa = ldfrag(&xs[xrow0][ks*32+k0]);
            bf16x8 bfb = ldfrag(&xs[xrow1][ks*32+k0]);
            #pragma unroll
            for (int tm = 0; tm < 3; tm++) {
                bf16x8 af = ldfrag(w1l + (tm*3+ks)*512);
                c1[tm][0] = __builtin_amdgcn_mfma_f32_16x16x32_bf16(af, bfa, c1[tm][0], 0, 0, 0);
                c1[tm][1] = __builtin_amdgcn_mfma_f32_16x16x32_bf16(af, bfb, c1[tm][1], 0, 0, 0);
            }
        }
        __builtin_amdgcn_s_setprio(0);
        #pragma unroll
        for (int tm = 0; tm < 3; tm++) {
            int d0 = mh*48 + tm*16 + r0i;
            int dch = ch*CC + d0;
            float g0 = gelu_t(c1[tm][0][0] + b1[dch+0]);
            float g1 = gelu_t(c1[tm][0][1] + b1[dch+1]);
            float g2 = gelu_t(c1[tm][0][2] + b1[dch+2]);
            float g3 = gelu_t(c1[tm][0][3] + b1[dch+3]);
            *reinterpret_cast<uint2*>(&mc[xrow0][d0]) = make_uint2(cvtpk(g0,g1), cvtpk(g2,g3));
            float h0 = gelu_t(c1[tm][1][0] + b1[dch+0]);
            float h1 = gelu_t(c1[tm][1][1] + b1[dch+1]);
            float h2 = gelu_t(c1[tm][1][2] + b1[dch+2]);
            float h3 = gelu_t(c1[tm][1][3] + b1[dch+3]);
            *reinterpret_cast<uint2*>(&mc[xrow1][d0]) = make_uint2(cvtpk(h0,h1), cvtpk(h2,h3));
        }
        __syncthreads();               // mc complete (both M-halves)
        __builtin_amdgcn_s_setprio(1);
        #pragma unroll
        for (int ks = 0; ks < 3; ks++) {
            bf16x8 bfa = ldfrag(&mc[xrow0][ks*32+k0]);
            bf16x8 bfb = ldfrag(&mc[xrow1][ks*32+k0]);
            #pragma unroll
            for (int tm = 0; tm < 3; tm++) {
                bf16x8 af = ldfrag(w2l + (tm*3+ks)*512);
                ao[tm][0] = __builtin_amdgcn_mfma_f32_16x16x32_bf16(af, bfa, ao[tm][0], 0, 0, 0);
                ao[tm][1] = __builtin_amdgcn_mfma_f32_16x16x32_bf16(af, bfb, ao[tm][1], 0, 0, 0);
            }
        }
        __builtin_amdgcn_s_setprio(0);
        __syncthreads();               // GEMM2 reads done before next chunk overwrites mc
    }
    size_t ob = (size_t)b*CHW + hw0 + cg*32 + ln;
    #pragma unroll
    for (int tm = 0; tm < 3; tm++) {
        #pragma unroll
        for (int r = 0; r < 4; r++) {
            int o = mh*48 + tm*16 + r0i + r;
            size_t i0 = ob + (size_t)o*HWSZ;
            float bo = b2[o];
            xio[i0]      = xio[i0]      + bo + ao[tm][0][r];
            xio[i0 + 16] = xio[i0 + 16] + bo + ao[tm][1][r];
        }
    }
}

extern "C" void kernel_launch(void* const* d_in, const int* in_sizes, int n_in,
                              void* d_out, int out_size, void* d_ws, size_t ws_size,
                              hipStream_t stream) {
    (void)in_sizes; (void)n_in; (void)out_size; (void)ws_size;
    const float* x    = (const float*)d_in[0];
    const float* n1g  = (const float*)d_in[1];
    const float* n1b  = (const float*)d_in[2];
    const float* c1w  = (const float*)d_in[3];
    const float* c1b  = (const float*)d_in[4];
    const float* g1g  = (const float*)d_in[5];
    const float* g1b  = (const float*)d_in[6];
    const float* dww  = (const float*)d_in[7];
    const float* dwb  = (const float*)d_in[8];
    const float* g2g  = (const float*)d_in[9];
    const float* g2b  = (const float*)d_in[10];
    const float* tau1 = (const float*)d_in[11];
    const float* vth1 = (const float*)d_in[12];
    const float* tau2 = (const float*)d_in[13];
    const float* vth2 = (const float*)d_in[14];
    const float* c21w = (const float*)d_in[15];
    const float* c21b = (const float*)d_in[16];
    const float* c22w = (const float*)d_in[17];
    const float* c22b = (const float*)d_in[18];
    const float* g3g  = (const float*)d_in[19];
    const float* g3b  = (const float*)d_in[20];
    const float* c3w  = (const float*)d_in[21];
    const float* c3b  = (const float*)d_in[22];
    const float* n2g  = (const float*)d_in[23];
    const float* n2b  = (const float*)d_in[24];
    const float* f1w  = (const float*)d_in[25];
    const float* f1b  = (const float*)d_in[26];
    const float* f2w  = (const float*)d_in[27];
    const float* f2b  = (const float*)d_in[28];
    float* out = (float*)d_out;

    unsigned short* A   = (unsigned short*)d_ws;     // bf16 NTOT buffers (A also reused as u8 spikes)
    unsigned short* Bb  = A  + NTOT;
    unsigned short* Cc  = Bb + NTOT;
    unsigned short* WBF = Cc + NTOT;                 // 110592 bf16 weights (fragment-repacked)
    float2* part0 = (float2*)(WBF + 110592);         // x stats partials      (64*32)
    float2* part1 = part0 + 64*32;                   // conv1 out partials    (64*49)
    float2* part2 = part1 + 64*49;                   // dw out partials       (64*96)
    float2* part3 = part2 + 64*96;                   // dual out partials     (64*49)
    float2* part4 = part3 + 64*49;                   // x2 partials           (64*49)

    const unsigned short* Wc1  = WBF;
    const unsigned short* Wc21 = WBF + 9216;
    const unsigned short* Wc22 = WBF + 18432;
    const unsigned short* Wc3  = WBF + 27648;

    unsigned char* Au8 = (unsigned char*)A;          // u8 spike buffers (xlr)
    unsigned char* Cu8 = (unsigned char*)Cc;         // (xtd)

    dim3 gStat(S_SPLIT, BB);
    dim3 gPair(HWSZ/64, BB/2);      // (49, 32)
    dim3 gSing(HWSZ/64, BB);        // (49, 64)

    wconv<<<432,256,0,stream>>>(c1w, c21w, c22w, c3w, f1w, f2w, WBF);
    gn_partial<<<gStat,256,0,stream>>>(x, part0);
    convk<false,false,S_SPLIT><<<gPair,256,0,stream>>>(x, Wc1, c1b, part0, n1g, n1b, nullptr, A, part1);  // t1 -> A (bf16)
    dw_fused<<<BB*CC,256,0,stream>>>(A, dww, dwb, part1, g1g, g1b, Bb, part2);                            // t2 -> B
    lif_hw<<<BB*CC/2,256,0,stream>>>(Bb, Au8, Cu8, part2, g2g, g2b, tau1, vth1, tau2, vth2);              // u8 spikes -> A,C
    dual_mfma<<<gSing,256,0,stream>>>(Au8, Cu8, Wc21, c21b, Wc22, c22b, Bb, part3);                       // h3 -> B
    convk<true,true,49><<<gPair,256,0,stream>>>(Bb, Wc3, c3b, part3, g3g, g3b, x, out, part4);            // x2 -> d_out
    mlp_mfma<<<gSing,256,0,stream>>>(out, part4, n2g, n2b, WBF, f1b, f2b);                                // out = x2 + mlp
}

// Round 19
// 268.683 us; speedup vs baseline: 1.0352x; 1.0352x over previous
//
#include <hip/hip_runtime.h>

#define BB 64
#define CC 96
#define HH 56
#define WW 56
#define HWSZ (HH*WW)          // 3136
#define CHW (CC*HWSZ)         // 301056
#define NTOT ((size_t)BB*CHW) // 19267584
#define S_SPLIT 32
#define CHUNK (CHW/S_SPLIT)   // 9408
#define HD 384
#define NP 104                // LDS row pitch (ushorts): 208B rows, 16B-aligned

typedef float f32x4  __attribute__((ext_vector_type(4)));
typedef float f32x4v __attribute__((ext_vector_type(4)));
typedef short bf16x8 __attribute__((ext_vector_type(8)));
typedef unsigned short u16x4 __attribute__((ext_vector_type(4)));

__device__ __forceinline__ unsigned short f2bf(float f) {
    unsigned int u = __float_as_uint(f);
    u = (u + 0x7FFFu + ((u >> 16) & 1u)) >> 16;   // RNE
    return (unsigned short)u;
}
// HW packed convert: 2 f32 -> packed 2x bf16 (RNE), ONE VALU op
__device__ __forceinline__ unsigned int cvtpk(float lo, float hi) {
    unsigned int r;
    asm("v_cvt_pk_bf16_f32 %0, %1, %2" : "=v"(r) : "v"(lo), "v"(hi));
    return r;
}
__device__ __forceinline__ unsigned short cvt1(float x) {
    return (unsigned short)cvtpk(x, x);
}
__device__ __forceinline__ float bf2f(unsigned short u) {
    return __uint_as_float(((unsigned int)u) << 16);
}
// tanh-approx GELU: |err| vs exact erf-gelu ~1e-3.
__device__ __forceinline__ float gelu_t(float x) {
    float s = x*x;
    float q = __builtin_fmaf(s, 0.102943f, 2.3021953f) * x;   // 2y*log2e
    float t = exp2f(q);
    float r = __builtin_amdgcn_rcpf(1.0f + t);
    return __builtin_fmaf(-x, r, x);                          // x - x/(1+e^{2y})
}
__device__ __forceinline__ bf16x8 ldfrag(const unsigned short* p) {
    return *reinterpret_cast<const bf16x8*>(p);
}
// inline GN-stats finalize
template<int NPART>
__device__ __forceinline__ float2 stats_from_parts(const float2* __restrict__ part, int b) {
    int lane = threadIdx.x & 63;
    float s = 0.f, q = 0.f;
    for (int i = lane; i < NPART; i += 64) {
        float2 v = part[b*NPART + i];
        s += v.x; q += v.y;
    }
    #pragma unroll
    for (int off = 32; off > 0; off >>= 1) {
        s += __shfl_down(s, off);
        q += __shfl_down(q, off);
    }
    s = __shfl(s, 0); q = __shfl(q, 0);
    float mean = s / (float)CHW;
    float var  = q / (float)CHW - mean*mean;
    return make_float2(mean, rsqrtf(var + 1e-5f));
}

// ================= weight pre-convert + MFMA-fragment repack (once) =================
__global__ __launch_bounds__(256) void wconv(const float* __restrict__ c1w, const float* __restrict__ c21w,
        const float* __restrict__ c22w, const float* __restrict__ c3w,
        const float* __restrict__ f1w, const float* __restrict__ f2w,
        unsigned short* __restrict__ wbf) {
    int i = blockIdx.x*256 + threadIdx.x;           // 110592 total
    int blk = i / 9216;
    int idx = i - blk*9216;
    int tm   = idx / 1536;
    int rem  = idx - tm*1536;
    int ks   = rem / 512;
    int rem2 = rem - ks*512;
    int lane = rem2 >> 3;
    int j    = rem2 & 7;
    int row = tm*16 + (lane & 15);
    int col = ks*32 + (lane >> 4)*8 + j;
    float v;
    if      (blk == 0) v = c1w [row*CC + col];
    else if (blk == 1) v = c21w[row*CC + col];
    else if (blk == 2) v = c22w[row*CC + col];
    else if (blk == 3) v = c3w [row*CC + col];
    else if (blk <  8) v = f1w[((blk-4)*CC + row)*CC + col];
    else               v = f2w[row*HD + (blk-8)*CC + col];
    wbf[i] = f2bf(v);
}

// ================= GN stats on x, float4 =================
__global__ __launch_bounds__(256) void gn_partial(const float* __restrict__ in, float2* __restrict__ part) {
    int b = blockIdx.y, s = blockIdx.x;
    const float4* p = (const float4*)(in + (size_t)b*CHW + (size_t)s*CHUNK);
    float sum = 0.f, sq = 0.f;
    for (int i = threadIdx.x; i < CHUNK/4; i += 256) {
        float4 v = p[i];
        sum += v.x+v.y+v.z+v.w;
        sq  += v.x*v.x+v.y*v.y+v.z*v.z+v.w*v.w;
    }
    #pragma unroll
    for (int off = 32; off > 0; off >>= 1) {
        sum += __shfl_down(sum, off);
        sq  += __shfl_down(sq,  off);
    }
    __shared__ float2 red[4];
    int wid = threadIdx.x >> 6, lane = threadIdx.x & 63;
    if (lane == 0) red[wid] = make_float2(sum, sq);
    __syncthreads();
    if (threadIdx.x == 0) {
        for (int i = 1; i < 4; i++) { sum += red[i].x; sq += red[i].y; }
        part[b*S_SPLIT + s] = make_float2(sum, sq);
    }
}

// ================= batch-paired 1x1 conv, M-split waves, 4-col vectorized staging =================
template<bool IN_BF, bool OUT_RES, int NPART>
__global__ __launch_bounds__(256) void convk(const void* __restrict__ in_,
        const unsigned short* __restrict__ wbf, const float* __restrict__ bias,
        const float2* __restrict__ part_in, const float* __restrict__ gam, const float* __restrict__ bet,
        const float* __restrict__ res, void* __restrict__ out_, float2* __restrict__ part_out) {
    __shared__ unsigned short xs[128][NP];
    __shared__ float af0[CC], bf0[CC], af1[CC], bf1[CC];
    __shared__ float2 red[4];
    int tid = threadIdx.x;
    int b0 = blockIdx.y, b1 = b0 + 32;
    int hw0 = blockIdx.x * 64;
    int lane = tid & 63, wv = tid >> 6;
    int mh = wv >> 1, cg = wv & 1;
    bf16x8 wfr[9];
    {
        const unsigned short* wl = wbf + mh*4608 + lane*8;
        #pragma unroll
        for (int i = 0; i < 9; i++) wfr[i] = ldfrag(wl + i*512);
    }
    float2 st0 = stats_from_parts<NPART>(part_in, b0);
    float2 st1 = stats_from_parts<NPART>(part_in, b1);
    if (tid < CC) {
        float a0 = st0.y * gam[tid];
        af0[tid] = a0; bf0[tid] = __builtin_fmaf(-st0.x, a0, bet[tid]);
        float a1 = st1.y * gam[tid];
        af1[tid] = a1; bf1[tid] = __builtin_fmaf(-st1.x, a1, bet[tid]);
    }
    __syncthreads();
    {
        // 4 cols/thread per c-plane: float4 (f32) or u16x4 (bf16) loads
        int colq = (tid & 15) * 4;
        for (int c4 = (tid >> 4)*4; c4 < CC; c4 += 64) {
            float v0[4][4], v1[4][4];
            #pragma unroll
            for (int j = 0; j < 4; j++) {
                int c = c4 + j;
                size_t off0 = (size_t)b0*CHW + (size_t)c*HWSZ + hw0 + colq;
                size_t off1 = (size_t)b1*CHW + (size_t)c*HWSZ + hw0 + colq;
                if (IN_BF) {
                    u16x4 u0 = *reinterpret_cast<const u16x4*>((const unsigned short*)in_ + off0);
                    u16x4 u1 = *reinterpret_cast<const u16x4*>((const unsigned short*)in_ + off1);
                    #pragma unroll
                    for (int jj = 0; jj < 4; jj++) {
                        v0[j][jj] = __builtin_fmaf(bf2f((unsigned short)u0[jj]), af0[c], bf0[c]);
                        v1[j][jj] = __builtin_fmaf(bf2f((unsigned short)u1[jj]), af1[c], bf1[c]);
                    }
                } else {
                    f32x4v f0 = *reinterpret_cast<const f32x4v*>((const float*)in_ + off0);
                    f32x4v f1 = *reinterpret_cast<const f32x4v*>((const float*)in_ + off1);
                    #pragma unroll
                    for (int jj = 0; jj < 4; jj++) {
                        v0[j][jj] = __builtin_fmaf(f0[jj], af0[c], bf0[c]);
                        v1[j][jj] = __builtin_fmaf(f1[jj], af1[c], bf1[c]);
                    }
                }
            }
            #pragma unroll
            for (int jj = 0; jj < 4; jj++) {
                *reinterpret_cast<uint2*>(&xs[colq+jj][c4]) =
                    make_uint2(cvtpk(v0[0][jj],v0[1][jj]), cvtpk(v0[2][jj],v0[3][jj]));
                *reinterpret_cast<uint2*>(&xs[64+colq+jj][c4]) =
                    make_uint2(cvtpk(v1[0][jj],v1[1][jj]), cvtpk(v1[2][jj],v1[3][jj]));
            }
        }
    }
    __syncthreads();
    int ln = lane & 15, k0 = (lane >> 4)*8, r0i = (lane >> 4)*4;
    f32x4 acc[3][4];
    #pragma unroll
    for (int t = 0; t < 3; t++)
        #pragma unroll
        for (int x = 0; x < 4; x++) acc[t][x] = (f32x4){0,0,0,0};
    __builtin_amdgcn_s_setprio(1);
    #pragma unroll
    for (int ks = 0; ks < 3; ks++) {
        bf16x8 bfr[4];
        #pragma unroll
        for (int xr = 0; xr < 4; xr++) bfr[xr] = ldfrag(&xs[cg*64 + xr*16 + ln][ks*32+k0]);
        #pragma unroll
        for (int tm = 0; tm < 3; tm++) {
            #pragma unroll
            for (int xr = 0; xr < 4; xr++)
                acc[tm][xr] = __builtin_amdgcn_mfma_f32_16x16x32_bf16(wfr[tm*3+ks], bfr[xr], acc[tm][xr], 0, 0, 0);
        }
    }
    __builtin_amdgcn_s_setprio(0);
    size_t obase = (size_t)(cg ? b1 : b0)*CHW + hw0;
    float s = 0.f, q = 0.f;
    #pragma unroll
    for (int tm = 0; tm < 3; tm++) {
        #pragma unroll
        for (int xr = 0; xr < 4; xr++) {
            #pragma unroll
            for (int r = 0; r < 4; r++) {
                int o = mh*48 + tm*16 + r0i + r;
                size_t idx = obase + (size_t)o*HWSZ + xr*16 + ln;
                float v = acc[tm][xr][r] + bias[o];
                if (OUT_RES) { v += res[idx]; ((float*)out_)[idx] = v; }
                else         { ((unsigned short*)out_)[idx] = cvt1(v); }
                s += v; q += v*v;
            }
        }
    }
    #pragma unroll
    for (int off = 32; off > 0; off >>= 1) { s += __shfl_down(s, off); q += __shfl_down(q, off); }
    if (lane == 0) red[wv] = make_float2(s, q);
    __syncthreads();
    if (tid == 0) {
        part_out[b0*49 + blockIdx.x] = make_float2(red[0].x + red[2].x, red[0].y + red[2].y);
        part_out[b1*49 + blockIdx.x] = make_float2(red[1].x + red[3].x, red[1].y + red[3].y);
    }
}

// ================= depthwise 3x3: vectorized stage-in =================
__global__ __launch_bounds__(256) void dw_fused(const unsigned short* __restrict__ t1,
        const float* __restrict__ dww, const float* __restrict__ dwb,
        const float2* __restrict__ part_in, const float* __restrict__ gam, const float* __restrict__ bet,
        unsigned short* __restrict__ t2, float2* __restrict__ part_out) {
    __shared__ float tile[HH*57];
    __shared__ float2 red[4];
    int bc = blockIdx.x;
    int b = bc / CC, c = bc - b*CC;
    int tid = threadIdx.x;
    float2 st = stats_from_parts<49>(part_in, b);
    float ga = gam[c]*st.y;
    float bb = __builtin_fmaf(-st.x, ga, bet[c]);
    const unsigned short* ip = t1 + (size_t)bc*HWSZ;
    for (int i = tid; i < HWSZ/4; i += 256) {
        u16x4 v = *reinterpret_cast<const u16x4*>(ip + (size_t)i*4);
        int h = i / 14;
        int w0 = (i - h*14)*4;
        float* tp = &tile[h*57 + w0];
        #pragma unroll
        for (int j = 0; j < 4; j++)
            tp[j] = gelu_t(__builtin_fmaf(bf2f((unsigned short)v[j]), ga, bb));
    }
    __syncthreads();
    float w00=dww[c*9+0],w01=dww[c*9+1],w02=dww[c*9+2],
          w10=dww[c*9+3],w11=dww[c*9+4],w12=dww[c*9+5],
          w20=dww[c*9+6],w21=dww[c*9+7],w22=dww[c*9+8];
    float bs = dwb[c];
    unsigned short* op = t2 + (size_t)bc*HWSZ;
    float s = 0.f, q = 0.f;
    for (int i = tid; i < HWSZ; i += 256) {
        int h = i/WW, w_ = i - h*WW;
        float acc = bs;
        int up = h > 0, dn = h < HH-1, lf = w_ > 0, rt = w_ < WW-1;
        const float* rm = &tile[(h-1)*57 + w_];
        const float* r0p = &tile[h*57 + w_];
        const float* rp = &tile[(h+1)*57 + w_];
        if (up) { if (lf) acc += rm[-1]*w00; acc += rm[0]*w01; if (rt) acc += rm[1]*w02; }
        if (lf) acc += r0p[-1]*w10;
        acc += r0p[0]*w11;
        if (rt) acc += r0p[1]*w12;
        if (dn) { if (lf) acc += rp[-1]*w20; acc += rp[0]*w21; if (rt) acc += rp[1]*w22; }
        op[i] = cvt1(acc);
        s += acc; q += acc*acc;
    }
    #pragma unroll
    for (int off = 32; off > 0; off >>= 1) { s += __shfl_down(s, off); q += __shfl_down(q, off); }
    int wid = tid >> 6, lane = tid & 63;
    if (lane == 0) red[wid] = make_float2(s, q);
    __syncthreads();
    if (tid == 0) {
        for (int i = 1; i < 4; i++) { s += red[i].x; q += red[i].y; }
        part_out[bc] = make_float2(s, q);   // indexed [b*96+c]
    }
}

// ================= merged LIF: u8 spike outputs, packed coalesced writes (R17 best) =================
__global__ __launch_bounds__(64) void lif_hw(const unsigned short* __restrict__ t2,
        unsigned char* __restrict__ xlr, unsigned char* __restrict__ xtd,
        const float2* __restrict__ part_in, const float* __restrict__ gam, const float* __restrict__ bet,
        const float* __restrict__ tau1p, const float* __restrict__ vth1p,
        const float* __restrict__ tau2p, const float* __restrict__ vth2p) {
    __shared__ unsigned short tile[HH*58];
    __shared__ unsigned char spA[HH*60];
    int bc = blockIdx.x;
    int b = bc / CC, c = bc - b*CC;
    int tid = threadIdx.x;
    float2 st = stats_from_parts<96>(part_in, b);
    float ga = gam[c]*st.y;
    float bb = __builtin_fmaf(-st.x, ga, bet[c]);
    const unsigned short* ip = t2 + (size_t)bc*HWSZ;
    for (int i = tid; i < HWSZ/4; i += 64) {
        u16x4 v = *reinterpret_cast<const u16x4*>(ip + i*4);
        int h = i / 14;
        int w0 = (i - h*14)*4;
        unsigned short* tp = &tile[h*58 + w0];
        #pragma unroll
        for (int j = 0; j < 4; j++)
            tp[j] = cvt1(gelu_t(__builtin_fmaf(bf2f((unsigned short)v[j]), ga, bb)));
    }
    __syncthreads();
    const float tau1 = *tau1p, vth1 = *vth1p;
    if (tid < WW) {
        float u = 0.f, o = 0.f;
        for (int h = 0; h < HH; h++) {
            float xv = bf2f(tile[h*58 + tid]);
            u = xv + tau1*u*(1.f - o);
            o = (u - vth1 > 0.f) ? 1.f : 0.f;
            spA[h*60 + tid] = (o != 0.f) ? 1 : 0;
        }
    }
    __syncthreads();                 // spA complete; tile reads for H done
    const float tau2 = *tau2p, vth2 = *vth2p;
    if (tid < HH) {
        float u = 0.f, o = 0.f;
        int off = tid*58;
        for (int w_ = 0; w_ < WW; w_++) {
            float xv = bf2f(tile[off + w_]);
            u = xv + tau2*u*(1.f - o);
            o = (u - vth2 > 0.f) ? 1.f : 0.f;
            tile[off + w_] = (o != 0.f) ? 1 : 0;   // in-place: own row, already read
        }
    }
    __syncthreads();
    size_t base = (size_t)bc*HWSZ;
    unsigned int* lr32 = (unsigned int*)(xlr + base);
    unsigned int* td32 = (unsigned int*)(xtd + base);
    for (int i = tid; i < HWSZ/4; i += 64) {   // i*4 = h*56 + w0
        int h = i / 14;
        int w0 = (i - h*14)*4;
        unsigned int a = (unsigned int)spA[h*60+w0] | ((unsigned int)spA[h*60+w0+1]<<8)
                       | ((unsigned int)spA[h*60+w0+2]<<16) | ((unsigned int)spA[h*60+w0+3]<<24);
        unsigned int t = (unsigned int)(tile[h*58+w0]&1) | ((unsigned int)(tile[h*58+w0+1]&1)<<8)
                       | ((unsigned int)(tile[h*58+w0+2]&1)<<16) | ((unsigned int)(tile[h*58+w0+3]&1)<<24);
        lr32[i] = a;
        td32[i] = t;
    }
}

// ================= dual conv: u8 spike inputs (bit-test -> bf16) =================
__global__ __launch_bounds__(256) void dual_mfma(const unsigned char* __restrict__ xa_g, const unsigned char* __restrict__ xb_g,
        const unsigned short* __restrict__ w1bf, const float* __restrict__ b1,
        const unsigned short* __restrict__ w2bf, const float* __restrict__ b2,
        unsigned short* __restrict__ out, float2* __restrict__ part_out) {
    __shared__ unsigned short xa[64][NP];
    __shared__ unsigned short xb[64][NP];
    __shared__ float2 red[4];
    int tid = threadIdx.x;
    int b = blockIdx.y;
    int hw0 = blockIdx.x * 64;
    {
        int colq = (tid & 15) * 4;
        const unsigned char* ap = xa_g + (size_t)b*CHW + hw0 + colq;
        const unsigned char* bp = xb_g + (size_t)b*CHW + hw0 + colq;
        for (int c4 = (tid >> 4)*4; c4 < CC; c4 += 64) {
            unsigned int ua[4], ub[4];
            #pragma unroll
            for (int j = 0; j < 4; j++) {
                ua[j] = *reinterpret_cast<const unsigned int*>(ap + (size_t)(c4+j)*HWSZ);
                ub[j] = *reinterpret_cast<const unsigned int*>(bp + (size_t)(c4+j)*HWSZ);
            }
            #pragma unroll
            for (int jj = 0; jj < 4; jj++) {
                unsigned int sh = jj*8;
                unsigned int la = (((ua[0]>>sh)&1u)*0x3F80u) | (((ua[1]>>sh)&1u)*0x3F800000u);
                unsigned int ha = (((ua[2]>>sh)&1u)*0x3F80u) | (((ua[3]>>sh)&1u)*0x3F800000u);
                unsigned int lb = (((ub[0]>>sh)&1u)*0x3F80u) | (((ub[1]>>sh)&1u)*0x3F800000u);
                unsigned int hb = (((ub[2]>>sh)&1u)*0x3F80u) | (((ub[3]>>sh)&1u)*0x3F800000u);
                *reinterpret_cast<uint2*>(&xa[colq+jj][c4]) = make_uint2(la, ha);
                *reinterpret_cast<uint2*>(&xb[colq+jj][c4]) = make_uint2(lb, hb);
            }
        }
    }
    __syncthreads();
    int lane = tid & 63, wv = tid >> 6;
    int mh = wv >> 1, cg = wv & 1;
    int ln = lane & 15, k0 = (lane >> 4)*8, r0i = (lane >> 4)*4;
    const unsigned short* wl1 = w1bf + mh*4608 + lane*8;
    const unsigned short* wl2 = w2bf + mh*4608 + lane*8;
    f32x4 acc1[3][2], acc2[3][2];
    #pragma unroll
    for (int t = 0; t < 3; t++) {
        acc1[t][0] = (f32x4){0,0,0,0}; acc1[t][1] = (f32x4){0,0,0,0};
        acc2[t][0] = (f32x4){0,0,0,0}; acc2[t][1] = (f32x4){0,0,0,0};
    }
    __builtin_amdgcn_s_setprio(1);
    #pragma unroll
    for (int ks = 0; ks < 3; ks++) {
        bf16x8 bfa0 = ldfrag(&xa[cg*32 + ln][ks*32+k0]);
        bf16x8 bfa1 = ldfrag(&xa[cg*32 + 16 + ln][ks*32+k0]);
        bf16x8 bfb0 = ldfrag(&xb[cg*32 + ln][ks*32+k0]);
        bf16x8 bfb1 = ldfrag(&xb[cg*32 + 16 + ln][ks*32+k0]);
        #pragma unroll
        for (int tm = 0; tm < 3; tm++) {
            bf16x8 af1 = ldfrag(wl1 + (tm*3+ks)*512);
            bf16x8 af2 = ldfrag(wl2 + (tm*3+ks)*512);
            acc1[tm][0] = __builtin_amdgcn_mfma_f32_16x16x32_bf16(af1, bfa0, acc1[tm][0], 0, 0, 0);
            acc1[tm][1] = __builtin_amdgcn_mfma_f32_16x16x32_bf16(af1, bfa1, acc1[tm][1], 0, 0, 0);
            acc2[tm][0] = __builtin_amdgcn_mfma_f32_16x16x32_bf16(af2, bfb0, acc2[tm][0], 0, 0, 0);
            acc2[tm][1] = __builtin_amdgcn_mfma_f32_16x16x32_bf16(af2, bfb1, acc2[tm][1], 0, 0, 0);
        }
    }
    __builtin_amdgcn_s_setprio(0);
    size_t ob = (size_t)b*CHW + hw0;
    float s = 0.f, q = 0.f;
    #pragma unroll
    for (int tm = 0; tm < 3; tm++) {
        #pragma unroll
        for (int xr = 0; xr < 2; xr++) {
            #pragma unroll
            for (int r = 0; r < 4; r++) {
                int o = mh*48 + tm*16 + r0i + r;
                float v = gelu_t(acc1[tm][xr][r] + b1[o]) + gelu_t(acc2[tm][xr][r] + b2[o]);
                out[ob + (size_t)o*HWSZ + cg*32 + xr*16 + ln] = cvt1(v);
                s += v; q += v*v;
            }
        }
    }
    #pragma unroll
    for (int off = 32; off > 0; off >>= 1) { s += __shfl_down(s, off); q += __shfl_down(q, off); }
    if (lane == 0) red[wv] = make_float2(s, q);
    __syncthreads();
    if (tid == 0) {
        for (int i = 1; i < 4; i++) { s += red[i].x; q += red[i].y; }
        part_out[b*49 + blockIdx.x] = make_float2(s, q);
    }
}

// ================= fused MLP: single batch/block, 256 threads, 5 blocks/CU (R17 best) =================
__global__ __launch_bounds__(256, 6) void mlp_mfma(float* __restrict__ xio, const float2* __restrict__ part_in,
        const float* __restrict__ gam, const float* __restrict__ bet,
        const unsigned short* __restrict__ wbf, const float* __restrict__ b1, const float* __restrict__ b2) {
    __shared__ unsigned short xs[64][NP];   // 13312 B
    __shared__ unsigned short mc[64][NP];   // 13312 B
    __shared__ float afc[CC], bfc[CC];      // +1024 -> 27648 B total, 5 blocks/CU
    int tid = threadIdx.x;
    int b = blockIdx.y;
    int hw0 = blockIdx.x * 64;
    int lane = tid & 63, wv = tid >> 6;
    int mh = wv >> 1;                 // M-half: rows mh*48..mh*48+47
    int cg = wv & 1;                  // col-half: cols cg*32..cg*32+31
    float2 st = stats_from_parts<49>(part_in, b);
    if (tid < CC) {
        float a = st.y * gam[tid];
        afc[tid] = a; bfc[tid] = __builtin_fmaf(-st.x, a, bet[tid]);
    }
    __syncthreads();
    {
        int col = tid & 63;
        size_t base = (size_t)b*CHW + hw0 + col;
        for (int c4 = (tid >> 6)*4; c4 < CC; c4 += 16) {
            float v[4];
            #pragma unroll
            for (int j = 0; j < 4; j++) {
                int c = c4 + j;
                float rv = xio[base + (size_t)c*HWSZ];
                v[j] = __builtin_fmaf(rv, afc[c], bfc[c]);
            }
            *reinterpret_cast<uint2*>(&xs[col][c4]) =
                make_uint2(cvtpk(v[0],v[1]), cvtpk(v[2],v[3]));
        }
    }
    __syncthreads();                   // xs fully staged
    int ln = lane & 15, k0 = (lane >> 4)*8;
    int r0i = (lane >> 4)*4;
    int xrow0 = cg*32 + ln;
    int xrow1 = xrow0 + 16;
    f32x4 ao[3][2];
    #pragma unroll
    for (int t = 0; t < 3; t++) { ao[t][0] = (f32x4){0,0,0,0}; ao[t][1] = (f32x4){0,0,0,0}; }
    for (int ch = 0; ch < 4; ch++) {
        const unsigned short* w1l = wbf + (4+ch)*9216 + mh*4608 + lane*8;
        const unsigned short* w2l = wbf + (8+ch)*9216 + mh*4608 + lane*8;
        f32x4 c1[3][2];
        #pragma unroll
        for (int t = 0; t < 3; t++) { c1[t][0] = (f32x4){0,0,0,0}; c1[t][1] = (f32x4){0,0,0,0}; }
        __builtin_amdgcn_s_setprio(1);
        #pragma unroll
        for (int ks = 0; ks < 3; ks++) {
            bf16x8 bfa = ldfrag(&xs[xrow0][ks*32+k0]);
            bf16x8 bfb = ldfrag(&xs[xrow1][ks*32+k0]);
            #pragma unroll
            for (int tm = 0; tm < 3; tm++) {
                bf16x8 af = ldfrag(w1l + (tm*3+ks)*512);
                c1[tm][0] = __builtin_amdgcn_mfma_f32_16x16x32_bf16(af, bfa, c1[tm][0], 0, 0, 0);
                c1[tm][1] = __builtin_amdgcn_mfma_f32_16x16x32_bf16(af, bfb, c1[tm][1], 0, 0, 0);
            }
        }
        __builtin_amdgcn_s_setprio(0);
        #pragma unroll
        for (int tm = 0; tm < 3; tm++) {
            int d0 = mh*48 + tm*16 + r0i;
            int dch = ch*CC + d0;
            float g0 = gelu_t(c1[tm][0][0] + b1[dch+0]);
            float g1 = gelu_t(c1[tm][0][1] + b1[dch+1]);
            float g2 = gelu_t(c1[tm][0][2] + b1[dch+2]);
            float g3 = gelu_t(c1[tm][0][3] + b1[dch+3]);
            *reinterpret_cast<uint2*>(&mc[xrow0][d0]) = make_uint2(cvtpk(g0,g1), cvtpk(g2,g3));
            float h0 = gelu_t(c1[tm][1][0] + b1[dch+0]);
            float h1 = gelu_t(c1[tm][1][1] + b1[dch+1]);
            float h2 = gelu_t(c1[tm][1][2] + b1[dch+2]);
            float h3 = gelu_t(c1[tm][1][3] + b1[dch+3]);
            *reinterpret_cast<uint2*>(&mc[xrow1][d0]) = make_uint2(cvtpk(h0,h1), cvtpk(h2,h3));
        }
        __syncthreads();               // mc complete (both M-halves)
        __builtin_amdgcn_s_setprio(1);
        #pragma unroll
        for (int ks = 0; ks < 3; ks++) {
            bf16x8 bfa = ldfrag(&mc[xrow0][ks*32+k0]);
            bf16x8 bfb = ldfrag(&mc[xrow1][ks*32+k0]);
            #pragma unroll
            for (int tm = 0; tm < 3; tm++) {
                bf16x8 af = ldfrag(w2l + (tm*3+ks)*512);
                ao[tm][0] = __builtin_amdgcn_mfma_f32_16x16x32_bf16(af, bfa, ao[tm][0], 0, 0, 0);
                ao[tm][1] = __builtin_amdgcn_mfma_f32_16x16x32_bf16(af, bfb, ao[tm][1], 0, 0, 0);
            }
        }
        __builtin_amdgcn_s_setprio(0);
        __syncthreads();               // GEMM2 reads done before next chunk overwrites mc
    }
    size_t ob = (size_t)b*CHW + hw0 + cg*32 + ln;
    #pragma unroll
    for (int tm = 0; tm < 3; tm++) {
        #pragma unroll
        for (int r = 0; r < 4; r++) {
            int o = mh*48 + tm*16 + r0i + r;
            size_t i0 = ob + (size_t)o*HWSZ;
            float bo = b2[o];
            xio[i0]      = xio[i0]      + bo + ao[tm][0][r];
            xio[i0 + 16] = xio[i0 + 16] + bo + ao[tm][1][r];
        }
    }
}

extern "C" void kernel_launch(void* const* d_in, const int* in_sizes, int n_in,
                              void* d_out, int out_size, void* d_ws, size_t ws_size,
                              hipStream_t stream) {
    (void)in_sizes; (void)n_in; (void)out_size; (void)ws_size;
    const float* x    = (const float*)d_in[0];
    const float* n1g  = (const float*)d_in[1];
    const float* n1b  = (const float*)d_in[2];
    const float* c1w  = (const float*)d_in[3];
    const float* c1b  = (const float*)d_in[4];
    const float* g1g  = (const float*)d_in[5];
    const float* g1b  = (const float*)d_in[6];
    const float* dww  = (const float*)d_in[7];
    const float* dwb  = (const float*)d_in[8];
    const float* g2g  = (const float*)d_in[9];
    const float* g2b  = (const float*)d_in[10];
    const float* tau1 = (const float*)d_in[11];
    const float* vth1 = (const float*)d_in[12];
    const float* tau2 = (const float*)d_in[13];
    const float* vth2 = (const float*)d_in[14];
    const float* c21w = (const float*)d_in[15];
    const float* c21b = (const float*)d_in[16];
    const float* c22w = (const float*)d_in[17];
    const float* c22b = (const float*)d_in[18];
    const float* g3g  = (const float*)d_in[19];
    const float* g3b  = (const float*)d_in[20];
    const float* c3w  = (const float*)d_in[21];
    const float* c3b  = (const float*)d_in[22];
    const float* n2g  = (const float*)d_in[23];
    const float* n2b  = (const float*)d_in[24];
    const float* f1w  = (const float*)d_in[25];
    const float* f1b  = (const float*)d_in[26];
    const float* f2w  = (const float*)d_in[27];
    const float* f2b  = (const float*)d_in[28];
    float* out = (float*)d_out;

    unsigned short* A   = (unsigned short*)d_ws;     // bf16 NTOT buffers (A also reused as u8 spikes)
    unsigned short* Bb  = A  + NTOT;
    unsigned short* Cc  = Bb + NTOT;
    unsigned short* WBF = Cc + NTOT;                 // 110592 bf16 weights (fragment-repacked)
    float2* part0 = (float2*)(WBF + 110592);         // x stats partials      (64*32)
    float2* part1 = part0 + 64*32;                   // conv1 out partials    (64*49)
    float2* part2 = part1 + 64*49;                   // dw out partials       (64*96)
    float2* part3 = part2 + 64*96;                   // dual out partials     (64*49)
    float2* part4 = part3 + 64*49;                   // x2 partials           (64*49)

    const unsigned short* Wc1  = WBF;
    const unsigned short* Wc21 = WBF + 9216;
    const unsigned short* Wc22 = WBF + 18432;
    const unsigned short* Wc3  = WBF + 27648;

    unsigned char* Au8 = (unsigned char*)A;          // u8 spike buffers (xlr)
    unsigned char* Cu8 = (unsigned char*)Cc;         // (xtd)

    dim3 gStat(S_SPLIT, BB);
    dim3 gPair(HWSZ/64, BB/2);      // (49, 32)
    dim3 gSing(HWSZ/64, BB);        // (49, 64)

    wconv<<<432,256,0,stream>>>(c1w, c21w, c22w, c3w, f1w, f2w, WBF);
    gn_partial<<<gStat,256,0,stream>>>(x, part0);
    convk<false,false,S_SPLIT><<<gPair,256,0,stream>>>(x, Wc1, c1b, part0, n1g, n1b, nullptr, A, part1);  // t1 -> A (bf16)
    dw_fused<<<BB*CC,256,0,stream>>>(A, dww, dwb, part1, g1g, g1b, Bb, part2);                            // t2 -> B
    lif_hw<<<BB*CC,64,0,stream>>>(Bb, Au8, Cu8, part2, g2g, g2b, tau1, vth1, tau2, vth2);                 // u8 spikes -> A,C
    dual_mfma<<<gSing,256,0,stream>>>(Au8, Cu8, Wc21, c21b, Wc22, c22b, Bb, part3);                       // h3 -> B
    convk<true,true,49><<<gPair,256,0,stream>>>(Bb, Wc3, c3b, part3, g3g, g3b, x, out, part4);            // x2 -> d_out
    mlp_mfma<<<gSing,256,0,stream>>>(out, part4, n2g, n2b, WBF, f1b, f2b);                                // out = x2 + mlp
}

// Round 20
// 261.804 us; speedup vs baseline: 1.0624x; 1.0263x over previous
//
#include <hip/hip_runtime.h>

#define BB 64
#define CC 96
#define HH 56
#define WW 56
#define HWSZ (HH*WW)          // 3136
#define CHW (CC*HWSZ)         // 301056
#define NTOT ((size_t)BB*CHW) // 19267584
#define S_SPLIT 32
#define CHUNK (CHW/S_SPLIT)   // 9408
#define HD 384
#define NP 104                // LDS row pitch (ushorts): 208B rows, 16B-aligned

typedef float f32x4  __attribute__((ext_vector_type(4)));
typedef float f32x4v __attribute__((ext_vector_type(4)));
typedef short bf16x8 __attribute__((ext_vector_type(8)));
typedef unsigned short u16x4 __attribute__((ext_vector_type(4)));

__device__ __forceinline__ unsigned short f2bf(float f) {
    unsigned int u = __float_as_uint(f);
    u = (u + 0x7FFFu + ((u >> 16) & 1u)) >> 16;   // RNE
    return (unsigned short)u;
}
// HW packed convert: 2 f32 -> packed 2x bf16 (RNE), ONE VALU op
__device__ __forceinline__ unsigned int cvtpk(float lo, float hi) {
    unsigned int r;
    asm("v_cvt_pk_bf16_f32 %0, %1, %2" : "=v"(r) : "v"(lo), "v"(hi));
    return r;
}
__device__ __forceinline__ unsigned short cvt1(float x) {
    return (unsigned short)cvtpk(x, x);
}
__device__ __forceinline__ float bf2f(unsigned short u) {
    return __uint_as_float(((unsigned int)u) << 16);
}
// tanh-approx GELU: |err| vs exact erf-gelu ~1e-3.
__device__ __forceinline__ float gelu_t(float x) {
    float s = x*x;
    float q = __builtin_fmaf(s, 0.102943f, 2.3021953f) * x;   // 2y*log2e
    float t = exp2f(q);
    float r = __builtin_amdgcn_rcpf(1.0f + t);
    return __builtin_fmaf(-x, r, x);                          // x - x/(1+e^{2y})
}
__device__ __forceinline__ bf16x8 ldfrag(const unsigned short* p) {
    return *reinterpret_cast<const bf16x8*>(p);
}
// inline GN-stats finalize
template<int NPART>
__device__ __forceinline__ float2 stats_from_parts(const float2* __restrict__ part, int b) {
    int lane = threadIdx.x & 63;
    float s = 0.f, q = 0.f;
    for (int i = lane; i < NPART; i += 64) {
        float2 v = part[b*NPART + i];
        s += v.x; q += v.y;
    }
    #pragma unroll
    for (int off = 32; off > 0; off >>= 1) {
        s += __shfl_down(s, off);
        q += __shfl_down(q, off);
    }
    s = __shfl(s, 0); q = __shfl(q, 0);
    float mean = s / (float)CHW;
    float var  = q / (float)CHW - mean*mean;
    return make_float2(mean, rsqrtf(var + 1e-5f));
}

// ================= weight pre-convert + MFMA-fragment repack (once) =================
__global__ __launch_bounds__(256) void wconv(const float* __restrict__ c1w, const float* __restrict__ c21w,
        const float* __restrict__ c22w, const float* __restrict__ c3w,
        const float* __restrict__ f1w, const float* __restrict__ f2w,
        unsigned short* __restrict__ wbf) {
    int i = blockIdx.x*256 + threadIdx.x;           // 110592 total
    int blk = i / 9216;
    int idx = i - blk*9216;
    int tm   = idx / 1536;
    int rem  = idx - tm*1536;
    int ks   = rem / 512;
    int rem2 = rem - ks*512;
    int lane = rem2 >> 3;
    int j    = rem2 & 7;
    int row = tm*16 + (lane & 15);
    int col = ks*32 + (lane >> 4)*8 + j;
    float v;
    if      (blk == 0) v = c1w [row*CC + col];
    else if (blk == 1) v = c21w[row*CC + col];
    else if (blk == 2) v = c22w[row*CC + col];
    else if (blk == 3) v = c3w [row*CC + col];
    else if (blk <  8) v = f1w[((blk-4)*CC + row)*CC + col];
    else               v = f2w[row*HD + (blk-8)*CC + col];
    wbf[i] = f2bf(v);
}

// ================= GN stats on x, float4 =================
__global__ __launch_bounds__(256) void gn_partial(const float* __restrict__ in, float2* __restrict__ part) {
    int b = blockIdx.y, s = blockIdx.x;
    const float4* p = (const float4*)(in + (size_t)b*CHW + (size_t)s*CHUNK);
    float sum = 0.f, sq = 0.f;
    for (int i = threadIdx.x; i < CHUNK/4; i += 256) {
        float4 v = p[i];
        sum += v.x+v.y+v.z+v.w;
        sq  += v.x*v.x+v.y*v.y+v.z*v.z+v.w*v.w;
    }
    #pragma unroll
    for (int off = 32; off > 0; off >>= 1) {
        sum += __shfl_down(sum, off);
        sq  += __shfl_down(sq,  off);
    }
    __shared__ float2 red[4];
    int wid = threadIdx.x >> 6, lane = threadIdx.x & 63;
    if (lane == 0) red[wid] = make_float2(sum, sq);
    __syncthreads();
    if (threadIdx.x == 0) {
        for (int i = 1; i < 4; i++) { sum += red[i].x; sq += red[i].y; }
        part[b*S_SPLIT + s] = make_float2(sum, sq);
    }
}

// ================= batch-paired 1x1 conv, M-split waves, 4-col vectorized staging =================
// Output is ALWAYS bf16 (cvt1); OUT_RES only controls the residual add. Stats from f32 values.
template<bool IN_BF, bool OUT_RES, int NPART>
__global__ __launch_bounds__(256) void convk(const void* __restrict__ in_,
        const unsigned short* __restrict__ wbf, const float* __restrict__ bias,
        const float2* __restrict__ part_in, const float* __restrict__ gam, const float* __restrict__ bet,
        const float* __restrict__ res, unsigned short* __restrict__ out_, float2* __restrict__ part_out) {
    __shared__ unsigned short xs[128][NP];
    __shared__ float af0[CC], bf0[CC], af1[CC], bf1[CC];
    __shared__ float2 red[4];
    int tid = threadIdx.x;
    int b0 = blockIdx.y, b1 = b0 + 32;
    int hw0 = blockIdx.x * 64;
    int lane = tid & 63, wv = tid >> 6;
    int mh = wv >> 1, cg = wv & 1;
    bf16x8 wfr[9];
    {
        const unsigned short* wl = wbf + mh*4608 + lane*8;
        #pragma unroll
        for (int i = 0; i < 9; i++) wfr[i] = ldfrag(wl + i*512);
    }
    float2 st0 = stats_from_parts<NPART>(part_in, b0);
    float2 st1 = stats_from_parts<NPART>(part_in, b1);
    if (tid < CC) {
        float a0 = st0.y * gam[tid];
        af0[tid] = a0; bf0[tid] = __builtin_fmaf(-st0.x, a0, bet[tid]);
        float a1 = st1.y * gam[tid];
        af1[tid] = a1; bf1[tid] = __builtin_fmaf(-st1.x, a1, bet[tid]);
    }
    __syncthreads();
    {
        // 4 cols/thread per c-plane: float4 (f32) or u16x4 (bf16) loads
        int colq = (tid & 15) * 4;
        for (int c4 = (tid >> 4)*4; c4 < CC; c4 += 64) {
            float v0[4][4], v1[4][4];
            #pragma unroll
            for (int j = 0; j < 4; j++) {
                int c = c4 + j;
                size_t off0 = (size_t)b0*CHW + (size_t)c*HWSZ + hw0 + colq;
                size_t off1 = (size_t)b1*CHW + (size_t)c*HWSZ + hw0 + colq;
                if (IN_BF) {
                    u16x4 u0 = *reinterpret_cast<const u16x4*>((const unsigned short*)in_ + off0);
                    u16x4 u1 = *reinterpret_cast<const u16x4*>((const unsigned short*)in_ + off1);
                    #pragma unroll
                    for (int jj = 0; jj < 4; jj++) {
                        v0[j][jj] = __builtin_fmaf(bf2f((unsigned short)u0[jj]), af0[c], bf0[c]);
                        v1[j][jj] = __builtin_fmaf(bf2f((unsigned short)u1[jj]), af1[c], bf1[c]);
                    }
                } else {
                    f32x4v f0 = *reinterpret_cast<const f32x4v*>((const float*)in_ + off0);
                    f32x4v f1 = *reinterpret_cast<const f32x4v*>((const float*)in_ + off1);
                    #pragma unroll
                    for (int jj = 0; jj < 4; jj++) {
                        v0[j][jj] = __builtin_fmaf(f0[jj], af0[c], bf0[c]);
                        v1[j][jj] = __builtin_fmaf(f1[jj], af1[c], bf1[c]);
                    }
                }
            }
            #pragma unroll
            for (int jj = 0; jj < 4; jj++) {
                *reinterpret_cast<uint2*>(&xs[colq+jj][c4]) =
                    make_uint2(cvtpk(v0[0][jj],v0[1][jj]), cvtpk(v0[2][jj],v0[3][jj]));
                *reinterpret_cast<uint2*>(&xs[64+colq+jj][c4]) =
                    make_uint2(cvtpk(v1[0][jj],v1[1][jj]), cvtpk(v1[2][jj],v1[3][jj]));
            }
        }
    }
    __syncthreads();
    int ln = lane & 15, k0 = (lane >> 4)*8, r0i = (lane >> 4)*4;
    f32x4 acc[3][4];
    #pragma unroll
    for (int t = 0; t < 3; t++)
        #pragma unroll
        for (int x = 0; x < 4; x++) acc[t][x] = (f32x4){0,0,0,0};
    __builtin_amdgcn_s_setprio(1);
    #pragma unroll
    for (int ks = 0; ks < 3; ks++) {
        bf16x8 bfr[4];
        #pragma unroll
        for (int xr = 0; xr < 4; xr++) bfr[xr] = ldfrag(&xs[cg*64 + xr*16 + ln][ks*32+k0]);
        #pragma unroll
        for (int tm = 0; tm < 3; tm++) {
            #pragma unroll
            for (int xr = 0; xr < 4; xr++)
                acc[tm][xr] = __builtin_amdgcn_mfma_f32_16x16x32_bf16(wfr[tm*3+ks], bfr[xr], acc[tm][xr], 0, 0, 0);
        }
    }
    __builtin_amdgcn_s_setprio(0);
    size_t obase = (size_t)(cg ? b1 : b0)*CHW + hw0;
    float s = 0.f, q = 0.f;
    #pragma unroll
    for (int tm = 0; tm < 3; tm++) {
        #pragma unroll
        for (int xr = 0; xr < 4; xr++) {
            #pragma unroll
            for (int r = 0; r < 4; r++) {
                int o = mh*48 + tm*16 + r0i + r;
                size_t idx = obase + (size_t)o*HWSZ + xr*16 + ln;
                float v = acc[tm][xr][r] + bias[o];
                if (OUT_RES) v += res[idx];
                out_[idx] = cvt1(v);
                s += v; q += v*v;
            }
        }
    }
    #pragma unroll
    for (int off = 32; off > 0; off >>= 1) { s += __shfl_down(s, off); q += __shfl_down(q, off); }
    if (lane == 0) red[wv] = make_float2(s, q);
    __syncthreads();
    if (tid == 0) {
        part_out[b0*49 + blockIdx.x] = make_float2(red[0].x + red[2].x, red[0].y + red[2].y);
        part_out[b1*49 + blockIdx.x] = make_float2(red[1].x + red[3].x, red[1].y + red[3].y);
    }
}

// ================= depthwise 3x3: vectorized stage-in =================
__global__ __launch_bounds__(256) void dw_fused(const unsigned short* __restrict__ t1,
        const float* __restrict__ dww, const float* __restrict__ dwb,
        const float2* __restrict__ part_in, const float* __restrict__ gam, const float* __restrict__ bet,
        unsigned short* __restrict__ t2, float2* __restrict__ part_out) {
    __shared__ float tile[HH*57];
    __shared__ float2 red[4];
    int bc = blockIdx.x;
    int b = bc / CC, c = bc - b*CC;
    int tid = threadIdx.x;
    float2 st = stats_from_parts<49>(part_in, b);
    float ga = gam[c]*st.y;
    float bb = __builtin_fmaf(-st.x, ga, bet[c]);
    const unsigned short* ip = t1 + (size_t)bc*HWSZ;
    for (int i = tid; i < HWSZ/4; i += 256) {
        u16x4 v = *reinterpret_cast<const u16x4*>(ip + (size_t)i*4);
        int h = i / 14;
        int w0 = (i - h*14)*4;
        float* tp = &tile[h*57 + w0];
        #pragma unroll
        for (int j = 0; j < 4; j++)
            tp[j] = gelu_t(__builtin_fmaf(bf2f((unsigned short)v[j]), ga, bb));
    }
    __syncthreads();
    float w00=dww[c*9+0],w01=dww[c*9+1],w02=dww[c*9+2],
          w10=dww[c*9+3],w11=dww[c*9+4],w12=dww[c*9+5],
          w20=dww[c*9+6],w21=dww[c*9+7],w22=dww[c*9+8];
    float bs = dwb[c];
    unsigned short* op = t2 + (size_t)bc*HWSZ;
    float s = 0.f, q = 0.f;
    for (int i = tid; i < HWSZ; i += 256) {
        int h = i/WW, w_ = i - h*WW;
        float acc = bs;
        int up = h > 0, dn = h < HH-1, lf = w_ > 0, rt = w_ < WW-1;
        const float* rm = &tile[(h-1)*57 + w_];
        const float* r0p = &tile[h*57 + w_];
        const float* rp = &tile[(h+1)*57 + w_];
        if (up) { if (lf) acc += rm[-1]*w00; acc += rm[0]*w01; if (rt) acc += rm[1]*w02; }
        if (lf) acc += r0p[-1]*w10;
        acc += r0p[0]*w11;
        if (rt) acc += r0p[1]*w12;
        if (dn) { if (lf) acc += rp[-1]*w20; acc += rp[0]*w21; if (rt) acc += rp[1]*w22; }
        op[i] = cvt1(acc);
        s += acc; q += acc*acc;
    }
    #pragma unroll
    for (int off = 32; off > 0; off >>= 1) { s += __shfl_down(s, off); q += __shfl_down(q, off); }
    int wid = tid >> 6, lane = tid & 63;
    if (lane == 0) red[wid] = make_float2(s, q);
    __syncthreads();
    if (tid == 0) {
        for (int i = 1; i < 4; i++) { s += red[i].x; q += red[i].y; }
        part_out[bc] = make_float2(s, q);   // indexed [b*96+c]
    }
}

// ================= merged LIF: u8 spike outputs, packed coalesced writes (R17 best) =================
__global__ __launch_bounds__(64) void lif_hw(const unsigned short* __restrict__ t2,
        unsigned char* __restrict__ xlr, unsigned char* __restrict__ xtd,
        const float2* __restrict__ part_in, const float* __restrict__ gam, const float* __restrict__ bet,
        const float* __restrict__ tau1p, const float* __restrict__ vth1p,
        const float* __restrict__ tau2p, const float* __restrict__ vth2p) {
    __shared__ unsigned short tile[HH*58];
    __shared__ unsigned char spA[HH*60];
    int bc = blockIdx.x;
    int b = bc / CC, c = bc - b*CC;
    int tid = threadIdx.x;
    float2 st = stats_from_parts<96>(part_in, b);
    float ga = gam[c]*st.y;
    float bb = __builtin_fmaf(-st.x, ga, bet[c]);
    const unsigned short* ip = t2 + (size_t)bc*HWSZ;
    for (int i = tid; i < HWSZ/4; i += 64) {
        u16x4 v = *reinterpret_cast<const u16x4*>(ip + i*4);
        int h = i / 14;
        int w0 = (i - h*14)*4;
        unsigned short* tp = &tile[h*58 + w0];
        #pragma unroll
        for (int j = 0; j < 4; j++)
            tp[j] = cvt1(gelu_t(__builtin_fmaf(bf2f((unsigned short)v[j]), ga, bb)));
    }
    __syncthreads();
    const float tau1 = *tau1p, vth1 = *vth1p;
    if (tid < WW) {
        float u = 0.f, o = 0.f;
        for (int h = 0; h < HH; h++) {
            float xv = bf2f(tile[h*58 + tid]);
            u = xv + tau1*u*(1.f - o);
            o = (u - vth1 > 0.f) ? 1.f : 0.f;
            spA[h*60 + tid] = (o != 0.f) ? 1 : 0;
        }
    }
    __syncthreads();                 // spA complete; tile reads for H done
    const float tau2 = *tau2p, vth2 = *vth2p;
    if (tid < HH) {
        float u = 0.f, o = 0.f;
        int off = tid*58;
        for (int w_ = 0; w_ < WW; w_++) {
            float xv = bf2f(tile[off + w_]);
            u = xv + tau2*u*(1.f - o);
            o = (u - vth2 > 0.f) ? 1.f : 0.f;
            tile[off + w_] = (o != 0.f) ? 1 : 0;   // in-place: own row, already read
        }
    }
    __syncthreads();
    size_t base = (size_t)bc*HWSZ;
    unsigned int* lr32 = (unsigned int*)(xlr + base);
    unsigned int* td32 = (unsigned int*)(xtd + base);
    for (int i = tid; i < HWSZ/4; i += 64) {   // i*4 = h*56 + w0
        int h = i / 14;
        int w0 = (i - h*14)*4;
        unsigned int a = (unsigned int)spA[h*60+w0] | ((unsigned int)spA[h*60+w0+1]<<8)
                       | ((unsigned int)spA[h*60+w0+2]<<16) | ((unsigned int)spA[h*60+w0+3]<<24);
        unsigned int t = (unsigned int)(tile[h*58+w0]&1) | ((unsigned int)(tile[h*58+w0+1]&1)<<8)
                       | ((unsigned int)(tile[h*58+w0+2]&1)<<16) | ((unsigned int)(tile[h*58+w0+3]&1)<<24);
        lr32[i] = a;
        td32[i] = t;
    }
}

// ================= dual conv: u8 spike inputs (bit-test -> bf16) =================
__global__ __launch_bounds__(256) void dual_mfma(const unsigned char* __restrict__ xa_g, const unsigned char* __restrict__ xb_g,
        const unsigned short* __restrict__ w1bf, const float* __restrict__ b1,
        const unsigned short* __restrict__ w2bf, const float* __restrict__ b2,
        unsigned short* __restrict__ out, float2* __restrict__ part_out) {
    __shared__ unsigned short xa[64][NP];
    __shared__ unsigned short xb[64][NP];
    __shared__ float2 red[4];
    int tid = threadIdx.x;
    int b = blockIdx.y;
    int hw0 = blockIdx.x * 64;
    {
        int colq = (tid & 15) * 4;
        const unsigned char* ap = xa_g + (size_t)b*CHW + hw0 + colq;
        const unsigned char* bp = xb_g + (size_t)b*CHW + hw0 + colq;
        for (int c4 = (tid >> 4)*4; c4 < CC; c4 += 64) {
            unsigned int ua[4], ub[4];
            #pragma unroll
            for (int j = 0; j < 4; j++) {
                ua[j] = *reinterpret_cast<const unsigned int*>(ap + (size_t)(c4+j)*HWSZ);
                ub[j] = *reinterpret_cast<const unsigned int*>(bp + (size_t)(c4+j)*HWSZ);
            }
            #pragma unroll
            for (int jj = 0; jj < 4; jj++) {
                unsigned int sh = jj*8;
                unsigned int la = (((ua[0]>>sh)&1u)*0x3F80u) | (((ua[1]>>sh)&1u)*0x3F800000u);
                unsigned int ha = (((ua[2]>>sh)&1u)*0x3F80u) | (((ua[3]>>sh)&1u)*0x3F800000u);
                unsigned int lb = (((ub[0]>>sh)&1u)*0x3F80u) | (((ub[1]>>sh)&1u)*0x3F800000u);
                unsigned int hb = (((ub[2]>>sh)&1u)*0x3F80u) | (((ub[3]>>sh)&1u)*0x3F800000u);
                *reinterpret_cast<uint2*>(&xa[colq+jj][c4]) = make_uint2(la, ha);
                *reinterpret_cast<uint2*>(&xb[colq+jj][c4]) = make_uint2(lb, hb);
            }
        }
    }
    __syncthreads();
    int lane = tid & 63, wv = tid >> 6;
    int mh = wv >> 1, cg = wv & 1;
    int ln = lane & 15, k0 = (lane >> 4)*8, r0i = (lane >> 4)*4;
    const unsigned short* wl1 = w1bf + mh*4608 + lane*8;
    const unsigned short* wl2 = w2bf + mh*4608 + lane*8;
    f32x4 acc1[3][2], acc2[3][2];
    #pragma unroll
    for (int t = 0; t < 3; t++) {
        acc1[t][0] = (f32x4){0,0,0,0}; acc1[t][1] = (f32x4){0,0,0,0};
        acc2[t][0] = (f32x4){0,0,0,0}; acc2[t][1] = (f32x4){0,0,0,0};
    }
    __builtin_amdgcn_s_setprio(1);
    #pragma unroll
    for (int ks = 0; ks < 3; ks++) {
        bf16x8 bfa0 = ldfrag(&xa[cg*32 + ln][ks*32+k0]);
        bf16x8 bfa1 = ldfrag(&xa[cg*32 + 16 + ln][ks*32+k0]);
        bf16x8 bfb0 = ldfrag(&xb[cg*32 + ln][ks*32+k0]);
        bf16x8 bfb1 = ldfrag(&xb[cg*32 + 16 + ln][ks*32+k0]);
        #pragma unroll
        for (int tm = 0; tm < 3; tm++) {
            bf16x8 af1 = ldfrag(wl1 + (tm*3+ks)*512);
            bf16x8 af2 = ldfrag(wl2 + (tm*3+ks)*512);
            acc1[tm][0] = __builtin_amdgcn_mfma_f32_16x16x32_bf16(af1, bfa0, acc1[tm][0], 0, 0, 0);
            acc1[tm][1] = __builtin_amdgcn_mfma_f32_16x16x32_bf16(af1, bfa1, acc1[tm][1], 0, 0, 0);
            acc2[tm][0] = __builtin_amdgcn_mfma_f32_16x16x32_bf16(af2, bfb0, acc2[tm][0], 0, 0, 0);
            acc2[tm][1] = __builtin_amdgcn_mfma_f32_16x16x32_bf16(af2, bfb1, acc2[tm][1], 0, 0, 0);
        }
    }
    __builtin_amdgcn_s_setprio(0);
    size_t ob = (size_t)b*CHW + hw0;
    float s = 0.f, q = 0.f;
    #pragma unroll
    for (int tm = 0; tm < 3; tm++) {
        #pragma unroll
        for (int xr = 0; xr < 2; xr++) {
            #pragma unroll
            for (int r = 0; r < 4; r++) {
                int o = mh*48 + tm*16 + r0i + r;
                float v = gelu_t(acc1[tm][xr][r] + b1[o]) + gelu_t(acc2[tm][xr][r] + b2[o]);
                out[ob + (size_t)o*HWSZ + cg*32 + xr*16 + ln] = cvt1(v);
                s += v; q += v*v;
            }
        }
    }
    #pragma unroll
    for (int off = 32; off > 0; off >>= 1) { s += __shfl_down(s, off); q += __shfl_down(q, off); }
    if (lane == 0) red[wv] = make_float2(s, q);
    __syncthreads();
    if (tid == 0) {
        for (int i = 1; i < 4; i++) { s += red[i].x; q += red[i].y; }
        part_out[b*49 + blockIdx.x] = make_float2(s, q);
    }
}

// ================= fused MLP: bf16 x2 input, f32 pure-store output =================
__global__ __launch_bounds__(256, 6) void mlp_mfma(const unsigned short* __restrict__ x2bf,
        float* __restrict__ out_f, const float2* __restrict__ part_in,
        const float* __restrict__ gam, const float* __restrict__ bet,
        const unsigned short* __restrict__ wbf, const float* __restrict__ b1, const float* __restrict__ b2) {
    __shared__ unsigned short xs[64][NP];   // 13312 B
    __shared__ unsigned short mc[64][NP];   // 13312 B
    __shared__ float afc[CC], bfc[CC];      // +1024 -> 27648 B total, 5 blocks/CU
    int tid = threadIdx.x;
    int b = blockIdx.y;
    int hw0 = blockIdx.x * 64;
    int lane = tid & 63, wv = tid >> 6;
    int mh = wv >> 1;                 // M-half: rows mh*48..mh*48+47
    int cg = wv & 1;                  // col-half: cols cg*32..cg*32+31
    float2 st = stats_from_parts<49>(part_in, b);
    if (tid < CC) {
        float a = st.y * gam[tid];
        afc[tid] = a; bfc[tid] = __builtin_fmaf(-st.x, a, bet[tid]);
    }
    __syncthreads();
    {
        // u32 loads: 2 cols/thread per c-plane (bf16 input)
        int colp = (tid & 31) * 2;
        size_t base = (size_t)b*CHW + hw0 + colp;
        for (int c4 = (tid >> 5)*4; c4 < CC; c4 += 32) {
            float v0[4], v1[4];
            #pragma unroll
            for (int j = 0; j < 4; j++) {
                int c = c4 + j;
                unsigned int u = *reinterpret_cast<const unsigned int*>(x2bf + base + (size_t)c*HWSZ);
                v0[j] = __builtin_fmaf(bf2f((unsigned short)u),       afc[c], bfc[c]);
                v1[j] = __builtin_fmaf(bf2f((unsigned short)(u>>16)), afc[c], bfc[c]);
            }
            *reinterpret_cast<uint2*>(&xs[colp][c4])   = make_uint2(cvtpk(v0[0],v0[1]), cvtpk(v0[2],v0[3]));
            *reinterpret_cast<uint2*>(&xs[colp+1][c4]) = make_uint2(cvtpk(v1[0],v1[1]), cvtpk(v1[2],v1[3]));
        }
    }
    __syncthreads();                   // xs fully staged
    int ln = lane & 15, k0 = (lane >> 4)*8;
    int r0i = (lane >> 4)*4;
    int xrow0 = cg*32 + ln;
    int xrow1 = xrow0 + 16;
    f32x4 ao[3][2];
    #pragma unroll
    for (int t = 0; t < 3; t++) { ao[t][0] = (f32x4){0,0,0,0}; ao[t][1] = (f32x4){0,0,0,0}; }
    for (int ch = 0; ch < 4; ch++) {
        const unsigned short* w1l = wbf + (4+ch)*9216 + mh*4608 + lane*8;
        const unsigned short* w2l = wbf + (8+ch)*9216 + mh*4608 + lane*8;
        f32x4 c1[3][2];
        #pragma unroll
        for (int t = 0; t < 3; t++) { c1[t][0] = (f32x4){0,0,0,0}; c1[t][1] = (f32x4){0,0,0,0}; }
        __builtin_amdgcn_s_setprio(1);
        #pragma unroll
        for (int ks = 0; ks < 3; ks++) {
            bf16x8 bfa = ldfrag(&xs[xrow0][ks*32+k0]);
            bf16x8 bfb = ldfrag(&xs[xrow1][ks*32+k0]);
            #pragma unroll
            for (int tm = 0; tm < 3; tm++) {
                bf16x8 af = ldfrag(w1l + (tm*3+ks)*512);
                c1[tm][0] = __builtin_amdgcn_mfma_f32_16x16x32_bf16(af, bfa, c1[tm][0], 0, 0, 0);
                c1[tm][1] = __builtin_amdgcn_mfma_f32_16x16x32_bf16(af, bfb, c1[tm][1], 0, 0, 0);
            }
        }
        __builtin_amdgcn_s_setprio(0);
        #pragma unroll
        for (int tm = 0; tm < 3; tm++) {
            int d0 = mh*48 + tm*16 + r0i;
            int dch = ch*CC + d0;
            float g0 = gelu_t(c1[tm][0][0] + b1[dch+0]);
            float g1 = gelu_t(c1[tm][0][1] + b1[dch+1]);
            float g2 = gelu_t(c1[tm][0][2] + b1[dch+2]);
            float g3 = gelu_t(c1[tm][0][3] + b1[dch+3]);
            *reinterpret_cast<uint2*>(&mc[xrow0][d0]) = make_uint2(cvtpk(g0,g1), cvtpk(g2,g3));
            float h0 = gelu_t(c1[tm][1][0] + b1[dch+0]);
            float h1 = gelu_t(c1[tm][1][1] + b1[dch+1]);
            float h2 = gelu_t(c1[tm][1][2] + b1[dch+2]);
            float h3 = gelu_t(c1[tm][1][3] + b1[dch+3]);
            *reinterpret_cast<uint2*>(&mc[xrow1][d0]) = make_uint2(cvtpk(h0,h1), cvtpk(h2,h3));
        }
        __syncthreads();               // mc complete (both M-halves)
        __builtin_amdgcn_s_setprio(1);
        #pragma unroll
        for (int ks = 0; ks < 3; ks++) {
            bf16x8 bfa = ldfrag(&mc[xrow0][ks*32+k0]);
            bf16x8 bfb = ldfrag(&mc[xrow1][ks*32+k0]);
            #pragma unroll
            for (int tm = 0; tm < 3; tm++) {
                bf16x8 af = ldfrag(w2l + (tm*3+ks)*512);
                ao[tm][0] = __builtin_amdgcn_mfma_f32_16x16x32_bf16(af, bfa, ao[tm][0], 0, 0, 0);
                ao[tm][1] = __builtin_amdgcn_mfma_f32_16x16x32_bf16(af, bfb, ao[tm][1], 0, 0, 0);
            }
        }
        __builtin_amdgcn_s_setprio(0);
        __syncthreads();               // GEMM2 reads done before next chunk overwrites mc
    }
    // epilogue: out = bf16(x2) + b2 + mlp  (pure store, no RMW on d_out)
    size_t ob = (size_t)b*CHW + hw0 + cg*32 + ln;
    #pragma unroll
    for (int tm = 0; tm < 3; tm++) {
        #pragma unroll
        for (int r = 0; r < 4; r++) {
            int o = mh*48 + tm*16 + r0i + r;
            size_t i0 = ob + (size_t)o*HWSZ;
            float bo = b2[o];
            out_f[i0]      = bf2f(x2bf[i0])      + bo + ao[tm][0][r];
            out_f[i0 + 16] = bf2f(x2bf[i0 + 16]) + bo + ao[tm][1][r];
        }
    }
}

extern "C" void kernel_launch(void* const* d_in, const int* in_sizes, int n_in,
                              void* d_out, int out_size, void* d_ws, size_t ws_size,
                              hipStream_t stream) {
    (void)in_sizes; (void)n_in; (void)out_size; (void)ws_size;
    const float* x    = (const float*)d_in[0];
    const float* n1g  = (const float*)d_in[1];
    const float* n1b  = (const float*)d_in[2];
    const float* c1w  = (const float*)d_in[3];
    const float* c1b  = (const float*)d_in[4];
    const float* g1g  = (const float*)d_in[5];
    const float* g1b  = (const float*)d_in[6];
    const float* dww  = (const float*)d_in[7];
    const float* dwb  = (const float*)d_in[8];
    const float* g2g  = (const float*)d_in[9];
    const float* g2b  = (const float*)d_in[10];
    const float* tau1 = (const float*)d_in[11];
    const float* vth1 = (const float*)d_in[12];
    const float* tau2 = (const float*)d_in[13];
    const float* vth2 = (const float*)d_in[14];
    const float* c21w = (const float*)d_in[15];
    const float* c21b = (const float*)d_in[16];
    const float* c22w = (const float*)d_in[17];
    const float* c22b = (const float*)d_in[18];
    const float* g3g  = (const float*)d_in[19];
    const float* g3b  = (const float*)d_in[20];
    const float* c3w  = (const float*)d_in[21];
    const float* c3b  = (const float*)d_in[22];
    const float* n2g  = (const float*)d_in[23];
    const float* n2b  = (const float*)d_in[24];
    const float* f1w  = (const float*)d_in[25];
    const float* f1b  = (const float*)d_in[26];
    const float* f2w  = (const float*)d_in[27];
    const float* f2b  = (const float*)d_in[28];
    float* out = (float*)d_out;

    unsigned short* A   = (unsigned short*)d_ws;     // bf16 NTOT buffers (A also reused as u8 spikes / x2bf)
    unsigned short* Bb  = A  + NTOT;
    unsigned short* Cc  = Bb + NTOT;
    unsigned short* WBF = Cc + NTOT;                 // 110592 bf16 weights (fragment-repacked)
    float2* part0 = (float2*)(WBF + 110592);         // x stats partials      (64*32)
    float2* part1 = part0 + 64*32;                   // conv1 out partials    (64*49)
    float2* part2 = part1 + 64*49;                   // dw out partials       (64*96)
    float2* part3 = part2 + 64*96;                   // dual out partials     (64*49)
    float2* part4 = part3 + 64*49;                   // x2 partials           (64*49)

    const unsigned short* Wc1  = WBF;
    const unsigned short* Wc21 = WBF + 9216;
    const unsigned short* Wc22 = WBF + 18432;
    const unsigned short* Wc3  = WBF + 27648;

    unsigned char* Au8 = (unsigned char*)A;          // u8 spike buffers (xlr)
    unsigned char* Cu8 = (unsigned char*)Cc;         // (xtd)

    dim3 gStat(S_SPLIT, BB);
    dim3 gPair(HWSZ/64, BB/2);      // (49, 32)
    dim3 gSing(HWSZ/64, BB);        // (49, 64)

    wconv<<<432,256,0,stream>>>(c1w, c21w, c22w, c3w, f1w, f2w, WBF);
    gn_partial<<<gStat,256,0,stream>>>(x, part0);
    convk<false,false,S_SPLIT><<<gPair,256,0,stream>>>(x, Wc1, c1b, part0, n1g, n1b, nullptr, A, part1);  // t1 -> A (bf16)
    dw_fused<<<BB*CC,256,0,stream>>>(A, dww, dwb, part1, g1g, g1b, Bb, part2);                            // t2 -> B
    lif_hw<<<BB*CC,64,0,stream>>>(Bb, Au8, Cu8, part2, g2g, g2b, tau1, vth1, tau2, vth2);                 // u8 spikes -> A,C
    dual_mfma<<<gSing,256,0,stream>>>(Au8, Cu8, Wc21, c21b, Wc22, c22b, Bb, part3);                       // h3 -> B
    convk<true,true,49><<<gPair,256,0,stream>>>(Bb, Wc3, c3b, part3, g3g, g3b, x, A, part4);              // x2 (bf16) -> A
    mlp_mfma<<<gSing,256,0,stream>>>(A, out, part4, n2g, n2b, WBF, f1b, f2b);                             // out = x2 + mlp (f32)
}